// Round 5
// baseline (749.735 us; speedup 1.0000x reference)
//
#include <hip/hip_runtime.h>
#include <math.h>

constexpr int BATCH = 4096;
constexpr int D_IN  = 784;
constexpr int F     = 512;
constexpr int NEC   = 512;   // codebook entries

typedef float f4_t  __attribute__((ext_vector_type(4)));
typedef float f16_t __attribute__((ext_vector_type(16)));

// ---------------- zero init (doubles) ----------------
__global__ void k_zero_d(double* p, int n) {
    int i = blockIdx.x * blockDim.x + threadIdx.x;
    if (i < n) p[i] = 0.0;
}

// ---------------- prep: pack codebooks for scalar-load access ----------------
// e1t[n][8] = E1[j][n] transpose; cn1[n] = seq sum of fl(e_j^2)  (same rounding as before)
// ecb3[n] = {e0, e1, fl(fl(e0^2)+fl(e1^2)), 0}
__global__ void k_prep(const float* __restrict__ E1, const float* __restrict__ E3,
                       float* __restrict__ e1t, float* __restrict__ cn1,
                       float* __restrict__ ecb3)
{
    int n = blockIdx.x * 64 + threadIdx.x;
    if (n >= NEC) return;
    float e0 = E1[n];
    e1t[n * 8 + 0] = e0;
    float c = __fmul_rn(e0, e0);
    #pragma unroll
    for (int j = 1; j < 8; ++j) {
        float ej = E1[j * NEC + n];
        e1t[n * 8 + j] = ej;
        c = __fadd_rn(c, __fmul_rn(ej, ej));
    }
    cn1[n] = c;
    float a0 = E3[n], a1 = E3[NEC + n];
    float cn = __fadd_rn(__fmul_rn(a0, a0), __fmul_rn(a1, a1));
    float4 v = make_float4(a0, a1, cn, 0.f);
    reinterpret_cast<float4*>(ecb3)[n] = v;
}

// ---- GEMM (NT) emulating BLAS sgemm: per-output sequential-k fma chain
// ---- within KC-panels (runtime KC), panel partials combined in order with fp32 adds.
// ---- Optional BN transform on A: a' = ((a - mu)*rs)*gamma + beta (np rounding).
template<bool RELU, bool BN>
__global__ __launch_bounds__(256) void k_gemm_np(
    const float* __restrict__ A, const float* __restrict__ Bw, float* __restrict__ C,
    int M, int N, int K, int KC,
    const float* __restrict__ mu, const float* __restrict__ rs,
    const float* __restrict__ gamma, const float* __restrict__ beta)
{
    __shared__ float As[16][68];
    __shared__ float Bs[16][68];
    const int t  = threadIdx.x;
    const int bm = blockIdx.y * 64, bn = blockIdx.x * 64;
    const int tm = (t >> 4) * 4, tn = (t & 15) * 4;
    const int rA = t >> 2;
    const int c4 = (t & 3) * 4;
    const float* Arow = A + (size_t)(bm + rA) * K;
    const float* Brow = Bw + (size_t)(bn + rA) * K;
    float tot[4][4];
    float accp[4][4] = {};
    bool first = true;
    for (int k0 = 0; k0 < K; k0 += 16) {
        float4 af = *reinterpret_cast<const float4*>(Arow + k0 + c4);
        float4 bf = *reinterpret_cast<const float4*>(Brow + k0 + c4);
        float av[4] = {af.x, af.y, af.z, af.w};
        if (BN) {
            #pragma unroll
            for (int u = 0; u < 4; ++u) {
                const int k = k0 + c4 + u;
                float d = __fsub_rn(av[u], mu[k]);
                d = __fmul_rn(d, rs[k]);
                d = __fmul_rn(d, gamma[k]);
                av[u] = __fadd_rn(d, beta[k]);
            }
        }
        As[c4 + 0][rA] = av[0]; As[c4 + 1][rA] = av[1];
        As[c4 + 2][rA] = av[2]; As[c4 + 3][rA] = av[3];
        Bs[c4 + 0][rA] = bf.x;  Bs[c4 + 1][rA] = bf.y;
        Bs[c4 + 2][rA] = bf.z;  Bs[c4 + 3][rA] = bf.w;
        __syncthreads();
        #pragma unroll
        for (int kk = 0; kk < 16; ++kk) {
            float4 a4 = *reinterpret_cast<const float4*>(&As[kk][tm]);
            float4 b4 = *reinterpret_cast<const float4*>(&Bs[kk][tn]);
            float aa[4] = {a4.x, a4.y, a4.z, a4.w};
            float bb[4] = {b4.x, b4.y, b4.z, b4.w};
            #pragma unroll
            for (int i = 0; i < 4; ++i)
                #pragma unroll
                for (int j = 0; j < 4; ++j)
                    accp[i][j] = fmaf(aa[i], bb[j], accp[i][j]);
        }
        __syncthreads();
        const int kend = k0 + 16;
        if ((kend % KC) == 0 || kend == K) {   // panel boundary: fold partial
            #pragma unroll
            for (int i = 0; i < 4; ++i)
                #pragma unroll
                for (int j = 0; j < 4; ++j) {
                    tot[i][j] = first ? accp[i][j] : __fadd_rn(tot[i][j], accp[i][j]);
                    accp[i][j] = 0.f;
                }
            first = false;
        }
    }
    #pragma unroll
    for (int i = 0; i < 4; ++i) {
        float r0 = RELU ? fmaxf(tot[i][0], 0.f) : tot[i][0];
        float r1 = RELU ? fmaxf(tot[i][1], 0.f) : tot[i][1];
        float r2 = RELU ? fmaxf(tot[i][2], 0.f) : tot[i][2];
        float r3 = RELU ? fmaxf(tot[i][3], 0.f) : tot[i][3];
        float4 r = make_float4(r0, r1, r2, r3);
        *reinterpret_cast<float4*>(&C[(size_t)(bm + tm + i) * N + bn + tn]) = r;
    }
}

// ---------------- wave reduce helper (fp64) ----------------
__device__ __forceinline__ double wave_reduce_add(double v) {
    #pragma unroll
    for (int off = 32; off; off >>= 1) v += __shfl_xor(v, off);
    return v;
}

// ---------------- fq21: dim-8 VQ, scalar-load codebook, np-fp32-exact ----------------
__global__ __launch_bounds__(256) void k_fq21_np(
    const float* __restrict__ h, const float* __restrict__ e1t,
    const float* __restrict__ cn1,
    float* __restrict__ qx, double* __restrict__ dacc)
{
    const int t = threadIdx.x;
    const int idx = blockIdx.x * 256 + t;
    const int b = idx >> 6, c = idx & 63;
    const float* hb = h + (size_t)b * F + c;
    float v[8];
    #pragma unroll
    for (int j = 0; j < 8; ++j) v[j] = hb[j * 64];
    float s[8];
    #pragma unroll
    for (int j = 0; j < 8; ++j) s[j] = __fmul_rn(v[j], v[j]);
    // numpy pairwise n=8: ((s0+s1)+(s2+s3)) + ((s4+s5)+(s6+s7))
    const float Aterm = __fadd_rn(
        __fadd_rn(__fadd_rn(s[0], s[1]), __fadd_rn(s[2], s[3])),
        __fadd_rn(__fadd_rn(s[4], s[5]), __fadd_rn(s[6], s[7])));
    float best = 3.4e38f; int bi = 0;
    float bq[8];   // codeword of current best (kept to avoid re-fetch)
    #pragma unroll
    for (int j = 0; j < 8; ++j) bq[j] = 0.f;
    for (int n0 = 0; n0 < NEC; n0 += 4) {
        f16_t e0v, e1v; f4_t cnv;
        const float* pe = e1t + (size_t)n0 * 8;
        const float* pc = cn1 + n0;
        asm volatile(
            "s_load_dwordx16 %0, %3, 0x0\n\t"
            "s_load_dwordx16 %1, %3, 0x40\n\t"
            "s_load_dwordx4  %2, %4, 0x0\n\t"
            "s_waitcnt lgkmcnt(0)"
            : "=s"(e0v), "=s"(e1v), "=s"(cnv)
            : "s"(pe), "s"(pc));
        #pragma unroll
        for (int u = 0; u < 4; ++u) {
            float e[8];
            #pragma unroll
            for (int j = 0; j < 8; ++j)
                e[j] = (u < 2) ? e0v[(u & 1) * 8 + j] : e1v[(u & 1) * 8 + j];
            float bsum = __fmul_rn(v[0], e[0]);
            #pragma unroll
            for (int j = 1; j < 8; ++j) bsum = fmaf(v[j], e[j], bsum);
            float d = __fadd_rn(__fsub_rn(Aterm, __fadd_rn(bsum, bsum)), cnv[u]);
            if (d < best) {
                best = d; bi = n0 + u;
                #pragma unroll
                for (int j = 0; j < 8; ++j) bq[j] = e[j];
            }
        }
    }
    (void)bi;
    double dsum = 0.0;
    float* qb = qx + (size_t)b * F + c;
    #pragma unroll
    for (int j = 0; j < 8; ++j) {
        float df = __fsub_rn(bq[j], v[j]);        // fl(q - x)
        dsum += (double)df * (double)df;
        qb[j * 64] = __fadd_rn(v[j], df);         // fl(x + fl(q - x))
    }
    dsum = wave_reduce_add(dsum);
    if ((t & 63) == 0) atomicAdd(dacc, dsum);
}

// ---------------- weight quantization: dim-16 VQ, numpy-fp32-exact (unchanged) ----------------
__global__ __launch_bounds__(256) void k_wq_np(
    const float* __restrict__ W2, const float* __restrict__ E,
    float* __restrict__ qW2, double* __restrict__ dacc)
{
    __shared__ float Es[NEC][16];
    __shared__ float Cn[NEC];
    const int t = threadIdx.x;
    for (int i = t; i < 16 * NEC; i += 256) Es[i & (NEC - 1)][i >> 9] = E[i];
    __syncthreads();
    for (int n = t; n < NEC; n += 256) {
        float c = __fmul_rn(Es[n][0], Es[n][0]);
        #pragma unroll
        for (int j = 1; j < 16; ++j)
            c = __fadd_rn(c, __fmul_rn(Es[n][j], Es[n][j]));
        Cn[n] = c;
    }
    __syncthreads();
    const int idx = blockIdx.x * 256 + t;   // 16384 vectors
    const int g = idx >> 6, c = idx & 63;
    float v[16];
    #pragma unroll
    for (int k = 0; k < 16; ++k)
        v[k] = W2[(size_t)(2 * g + (k & 1)) * F + 8 * c + (k >> 1)];
    float s[16];
    #pragma unroll
    for (int k = 0; k < 16; ++k) s[k] = __fmul_rn(v[k], v[k]);
    // numpy pairwise n=16: r_j = s_j + s_{j+8}; then 8-tree
    float r[8];
    #pragma unroll
    for (int j = 0; j < 8; ++j) r[j] = __fadd_rn(s[j], s[j + 8]);
    const float Aterm = __fadd_rn(
        __fadd_rn(__fadd_rn(r[0], r[1]), __fadd_rn(r[2], r[3])),
        __fadd_rn(__fadd_rn(r[4], r[5]), __fadd_rn(r[6], r[7])));
    float best = 3.4e38f; int bi = 0;
    for (int n = 0; n < NEC; ++n) {
        float bsum = __fmul_rn(v[0], Es[n][0]);
        #pragma unroll
        for (int k = 1; k < 16; ++k) bsum = fmaf(v[k], Es[n][k], bsum);
        float d = __fadd_rn(__fsub_rn(Aterm, __fadd_rn(bsum, bsum)), Cn[n]);
        if (d < best) { best = d; bi = n; }
    }
    double dsum = 0.0;
    #pragma unroll
    for (int k = 0; k < 16; ++k) {
        float df = __fsub_rn(Es[bi][k], v[k]);
        dsum += (double)df * (double)df;
        qW2[(size_t)(2 * g + (k & 1)) * F + 8 * c + (k >> 1)] = __fadd_rn(v[k], df);
    }
    dsum = wave_reduce_add(dsum);
    if ((t & 63) == 0) atomicAdd(dacc, dsum);
}

// ---------------- BN stats: numpy sequential fp32 over rows ----------------
__global__ void k_bn(const float* __restrict__ qx, float* __restrict__ mu, float* __restrict__ rs)
{
    int f = blockIdx.x * blockDim.x + threadIdx.x;
    if (f >= F) return;
    float acc = 0.f;
    for (int r = 0; r < BATCH; ++r) acc = __fadd_rn(acc, qx[(size_t)r * F + f]);
    float m = __fmul_rn(acc, 1.f / 4096.f);   // exact (/2^12)
    float acc2 = 0.f;
    for (int r = 0; r < BATCH; ++r) {
        float d = __fsub_rn(qx[(size_t)r * F + f], m);
        acc2 = __fadd_rn(acc2, __fmul_rn(d, d));
    }
    float var = __fmul_rn(acc2, 1.f / 4096.f);
    float w = __fadd_rn(var, 1e-5f);
    mu[f] = m;
    rs[f] = __fdiv_rn(1.0f, __fsqrt_rn(w));
}

// ---------------- fq22: dim-2 VQ, scalar-load codebook, np-fp32-exact ----------------
__global__ __launch_bounds__(256) void k_fq22_np(
    const float* __restrict__ h2, const float* __restrict__ ecb3,
    float* __restrict__ qx2, double* __restrict__ dacc)
{
    const int t = threadIdx.x;
    const int b = blockIdx.x;
    const float v0 = h2[(size_t)b * F + t];
    const float v1 = h2[(size_t)b * F + 256 + t];
    const float Aterm = __fadd_rn(__fmul_rn(v0, v0), __fmul_rn(v1, v1));
    float best = 3.4e38f;
    float be0 = 0.f, be1 = 0.f;
    for (int n0 = 0; n0 < NEC; n0 += 8) {
        f16_t c0, c1;
        const float* p = ecb3 + (size_t)n0 * 4;
        asm volatile(
            "s_load_dwordx16 %0, %2, 0x0\n\t"
            "s_load_dwordx16 %1, %2, 0x40\n\t"
            "s_waitcnt lgkmcnt(0)"
            : "=s"(c0), "=s"(c1) : "s"(p));
        #pragma unroll
        for (int u = 0; u < 8; ++u) {
            float e0 = (u < 4) ? c0[(u & 3) * 4 + 0] : c1[(u & 3) * 4 + 0];
            float e1 = (u < 4) ? c0[(u & 3) * 4 + 1] : c1[(u & 3) * 4 + 1];
            float cn = (u < 4) ? c0[(u & 3) * 4 + 2] : c1[(u & 3) * 4 + 2];
            float bsum = fmaf(v1, e1, __fmul_rn(v0, e0));   // k=2 fma chain
            float d = __fadd_rn(__fsub_rn(Aterm, __fadd_rn(bsum, bsum)), cn);
            if (d < best) { best = d; be0 = e0; be1 = e1; }
        }
    }
    float d0 = __fsub_rn(be0, v0), d1 = __fsub_rn(be1, v1);
    qx2[(size_t)b * F + t]       = __fadd_rn(v0, d0);
    qx2[(size_t)b * F + 256 + t] = __fadd_rn(v1, d1);
    double dsum = (double)d0 * d0 + (double)d1 * d1;
    dsum = wave_reduce_add(dsum);
    if ((t & 63) == 0) atomicAdd(dacc, dsum);
}

// ---------------- final thin GEMM: out[b,o] = sum_i qx2[b,i] * W3[o,i] ----------------
__global__ __launch_bounds__(256) void k_gemm3(
    const float* __restrict__ qx2, const float* __restrict__ W3, float* __restrict__ out)
{
    __shared__ float Ws[10 * F];
    const int t = threadIdx.x;
    for (int i = t; i < 10 * F; i += 256) Ws[i] = W3[i];
    __syncthreads();
    const int w = t >> 6, l = t & 63;
    const int b = blockIdx.x * 4 + w;
    const float* xb = qx2 + (size_t)b * F;
    double acc[10] = {};
    for (int i = l; i < F; i += 64) {
        double xv = (double)xb[i];
        #pragma unroll
        for (int o = 0; o < 10; ++o) acc[o] = fma(xv, (double)Ws[o * F + i], acc[o]);
    }
    #pragma unroll
    for (int o = 0; o < 10; ++o) {
        double a = wave_reduce_add(acc[o]);
        if (l == 0) out[(size_t)b * 10 + o] = (float)a;
    }
}

// ---------------- diff scalar ----------------
__global__ void k_findiff(const double* __restrict__ dacc, float* __restrict__ out)
{
    if (threadIdx.x == 0) {
        double d21 = dacc[0] * (1.0 / 2097152.0);   // 4096*64*8
        double dq  = dacc[1] * (1.0 / 262144.0);    // 256*64*16
        double d22 = dacc[2] * (1.0 / 2097152.0);   // 4096*256*2
        out[BATCH * 10] = (float)((d21 + d22) + dq);
    }
}

extern "C" void kernel_launch(void* const* d_in, const int* in_sizes, int n_in,
                              void* d_out, int out_size, void* d_ws, size_t ws_size,
                              hipStream_t stream)
{
    const float* x     = (const float*)d_in[0];
    const float* W1    = (const float*)d_in[1];
    const float* W2    = (const float*)d_in[2];
    const float* W3    = (const float*)d_in[3];
    const float* gamma = (const float*)d_in[4];
    const float* beta  = (const float*)d_in[5];
    const float* E1    = (const float*)d_in[6];   // [8,512]
    const float* E2    = (const float*)d_in[7];   // [16,512]
    const float* E3    = (const float*)d_in[8];   // [2,512]
    float* out = (float*)d_out;

    const int KC = 512;   // confirmed round 4 (BLIS/zen single-panel for K=512)

    char* ws = (char*)d_ws;
    float*  hf   = (float*)ws;                                 // 8 MB (h, then h2)
    float*  qxf  = (float*)(ws + (size_t) 8 * 1024 * 1024);    // 8 MB (qx, then qx2)
    float*  qW2f = (float*)(ws + (size_t)16 * 1024 * 1024);    // 1 MB
    float*  muf  = (float*)(ws + (size_t)17 * 1024 * 1024);    // 512 f32
    float*  rsf  = muf + F;                                    // 512 f32
    double* dacc = (double*)(ws + (size_t)17 * 1024 * 1024 + 4096);   // 3 doubles
    float*  e1t  = (float*)(ws + (size_t)17 * 1024 * 1024 + 8192);    // 512*8 f32 (16 KB)
    float*  cn1  = e1t + NEC * 8;                              // 512 f32
    float*  ecb3 = cn1 + NEC;                                  // 512*4 f32

    k_zero_d<<<1, 64, 0, stream>>>(dacc, 3);
    k_prep<<<8, 64, 0, stream>>>(E1, E3, e1t, cn1, ecb3);
    // h = relu(x @ W1^T)  — sgemm emulation, KC panels (784 = 512 + 272)
    k_gemm_np<true, false><<<dim3(F / 64, BATCH / 64), 256, 0, stream>>>(
        x, W1, hf, BATCH, F, D_IN, KC, nullptr, nullptr, nullptr, nullptr);
    // fq21 -> qx
    k_fq21_np<<<BATCH * 64 / 256, 256, 0, stream>>>(hf, e1t, cn1, qxf, dacc + 0);
    // weight quantization -> qW2
    k_wq_np<<<64, 256, 0, stream>>>(W2, E2, qW2f, dacc + 1);
    // BN stats (sequential fp32, numpy order)
    k_bn<<<2, 256, 0, stream>>>(qxf, muf, rsf);
    // h2 = relu(bn(qx) @ qW2^T) — K=512 = single panel -> pure sequential fma
    k_gemm_np<true, true><<<dim3(F / 64, BATCH / 64), 256, 0, stream>>>(
        qxf, qW2f, hf, BATCH, F, F, KC, muf, rsf, gamma, beta);
    // fq22 -> qx2
    k_fq22_np<<<BATCH, 256, 0, stream>>>(hf, ecb3, qxf, dacc + 2);
    // out = qx2 @ W3^T
    k_gemm3<<<BATCH / 4, 256, 0, stream>>>(qxf, W3, out);
    k_findiff<<<1, 64, 0, stream>>>(dacc, out);
}

// Round 6
// 734.920 us; speedup vs baseline: 1.0202x; 1.0202x over previous
//
#include <hip/hip_runtime.h>
#include <math.h>

constexpr int BATCH = 4096;
constexpr int D_IN  = 784;
constexpr int F     = 512;
constexpr int NEC   = 512;   // codebook entries

constexpr int   GRID_N = 64;     // fq22 spatial grid
constexpr float GCELL  = 0.25f;  // covers [0,16) x [0,16)
constexpr int   GCAP   = 96;     // max candidates per cell

// ---------------- zero init (doubles) ----------------
__global__ void k_zero_d(double* p, int n) {
    int i = blockIdx.x * blockDim.x + threadIdx.x;
    if (i < n) p[i] = 0.0;
}

// ---------------- prep: pack fq22 codebook {e0,e1,|e|^2,0} ----------------
__global__ void k_prep(const float* __restrict__ E3, float* __restrict__ ecb3)
{
    int n = blockIdx.x * 64 + threadIdx.x;
    if (n >= NEC) return;
    float a0 = E3[n], a1 = E3[NEC + n];
    float cn = __fadd_rn(__fmul_rn(a0, a0), __fmul_rn(a1, a1));
    reinterpret_cast<float4*>(ecb3)[n] = make_float4(a0, a1, cn, 0.f);
}

// ---------------- fq22 grid build: one thread per cell ----------------
// keep e if minDist2(e,cell) <= min_e'(maxDist2(e',cell)) + 0.01  (true-geometry
// margin 0.01 >> 5e-4 worst-case fp32-formula deviation -> provably superset)
__global__ void k_grid(const float* __restrict__ E3,
                       int* __restrict__ gcnt, short* __restrict__ glist)
{
    int cell = blockIdx.x * 256 + threadIdx.x;
    if (cell >= GRID_N * GRID_N) return;
    int cx = cell & (GRID_N - 1), cy = cell >> 6;
    float x0 = cx * GCELL, x1 = x0 + GCELL;
    float y0 = cy * GCELL, y1 = y0 + GCELL;
    float minUpper = 3.4e38f;
    for (int n = 0; n < NEC; ++n) {
        float ex = E3[n], ey = E3[NEC + n];
        float dxmax = fmaxf(x1 - ex, ex - x0);
        float dymax = fmaxf(y1 - ey, ey - y0);
        minUpper = fminf(minUpper, dxmax * dxmax + dymax * dymax);
    }
    float thr = minUpper + 0.01f;
    int cnt = 0;
    for (int n = 0; n < NEC; ++n) {
        float ex = E3[n], ey = E3[NEC + n];
        float dxmin = fmaxf(fmaxf(x0 - ex, ex - x1), 0.f);
        float dymin = fmaxf(fmaxf(y0 - ey, ey - y1), 0.f);
        if (dxmin * dxmin + dymin * dymin <= thr) {
            if (cnt < GCAP) glist[(size_t)cell * GCAP + cnt] = (short)n;
            ++cnt;
        }
    }
    gcnt[cell] = cnt;
}

// ---- GEMM (NT) emulating BLAS sgemm: per-output sequential-k fma chain
// ---- within KC-panels (runtime KC), panel partials combined in order with fp32 adds.
template<bool RELU, bool BN>
__global__ __launch_bounds__(256) void k_gemm_np(
    const float* __restrict__ A, const float* __restrict__ Bw, float* __restrict__ C,
    int M, int N, int K, int KC,
    const float* __restrict__ mu, const float* __restrict__ rs,
    const float* __restrict__ gamma, const float* __restrict__ beta)
{
    __shared__ float As[16][68];
    __shared__ float Bs[16][68];
    const int t  = threadIdx.x;
    const int bm = blockIdx.y * 64, bn = blockIdx.x * 64;
    const int tm = (t >> 4) * 4, tn = (t & 15) * 4;
    const int rA = t >> 2;
    const int c4 = (t & 3) * 4;
    const float* Arow = A + (size_t)(bm + rA) * K;
    const float* Brow = Bw + (size_t)(bn + rA) * K;
    float tot[4][4];
    float accp[4][4] = {};
    bool first = true;
    for (int k0 = 0; k0 < K; k0 += 16) {
        float4 af = *reinterpret_cast<const float4*>(Arow + k0 + c4);
        float4 bf = *reinterpret_cast<const float4*>(Brow + k0 + c4);
        float av[4] = {af.x, af.y, af.z, af.w};
        if (BN) {
            #pragma unroll
            for (int u = 0; u < 4; ++u) {
                const int k = k0 + c4 + u;
                float d = __fsub_rn(av[u], mu[k]);
                d = __fmul_rn(d, rs[k]);
                d = __fmul_rn(d, gamma[k]);
                av[u] = __fadd_rn(d, beta[k]);
            }
        }
        As[c4 + 0][rA] = av[0]; As[c4 + 1][rA] = av[1];
        As[c4 + 2][rA] = av[2]; As[c4 + 3][rA] = av[3];
        Bs[c4 + 0][rA] = bf.x;  Bs[c4 + 1][rA] = bf.y;
        Bs[c4 + 2][rA] = bf.z;  Bs[c4 + 3][rA] = bf.w;
        __syncthreads();
        #pragma unroll
        for (int kk = 0; kk < 16; ++kk) {
            float4 a4 = *reinterpret_cast<const float4*>(&As[kk][tm]);
            float4 b4 = *reinterpret_cast<const float4*>(&Bs[kk][tn]);
            float aa[4] = {a4.x, a4.y, a4.z, a4.w};
            float bb[4] = {b4.x, b4.y, b4.z, b4.w};
            #pragma unroll
            for (int i = 0; i < 4; ++i)
                #pragma unroll
                for (int j = 0; j < 4; ++j)
                    accp[i][j] = fmaf(aa[i], bb[j], accp[i][j]);
        }
        __syncthreads();
        const int kend = k0 + 16;
        if ((kend % KC) == 0 || kend == K) {   // panel boundary: fold partial
            #pragma unroll
            for (int i = 0; i < 4; ++i)
                #pragma unroll
                for (int j = 0; j < 4; ++j) {
                    tot[i][j] = first ? accp[i][j] : __fadd_rn(tot[i][j], accp[i][j]);
                    accp[i][j] = 0.f;
                }
            first = false;
        }
    }
    #pragma unroll
    for (int i = 0; i < 4; ++i) {
        float r0 = RELU ? fmaxf(tot[i][0], 0.f) : tot[i][0];
        float r1 = RELU ? fmaxf(tot[i][1], 0.f) : tot[i][1];
        float r2 = RELU ? fmaxf(tot[i][2], 0.f) : tot[i][2];
        float r3 = RELU ? fmaxf(tot[i][3], 0.f) : tot[i][3];
        float4 r = make_float4(r0, r1, r2, r3);
        *reinterpret_cast<float4*>(&C[(size_t)(bm + tm + i) * N + bn + tn]) = r;
    }
}

// ---------------- wave reduce helper (fp64) ----------------
__device__ __forceinline__ double wave_reduce_add(double v) {
    #pragma unroll
    for (int off = 32; off; off >>= 1) v += __shfl_xor(v, off);
    return v;
}

// ---------------- fq21: dim-8 VQ, LDS codebook, index-only tracking ----------------
__global__ __launch_bounds__(256) void k_fq21_np(
    const float* __restrict__ h, const float* __restrict__ E,
    float* __restrict__ qx, double* __restrict__ dacc)
{
    __shared__ float Es[NEC][8];
    __shared__ float Cn[NEC];
    const int t = threadIdx.x;
    for (int i = t; i < 8 * NEC; i += 256) Es[i & (NEC - 1)][i >> 9] = E[i];
    __syncthreads();
    for (int n = t; n < NEC; n += 256) {
        float c = __fmul_rn(Es[n][0], Es[n][0]);
        #pragma unroll
        for (int j = 1; j < 8; ++j)
            c = __fadd_rn(c, __fmul_rn(Es[n][j], Es[n][j]));
        Cn[n] = c;
    }
    __syncthreads();
    const int idx = blockIdx.x * 256 + t;
    const int b = idx >> 6, c = idx & 63;
    const float* hb = h + (size_t)b * F + c;
    float v[8];
    #pragma unroll
    for (int j = 0; j < 8; ++j) v[j] = hb[j * 64];
    float s[8];
    #pragma unroll
    for (int j = 0; j < 8; ++j) s[j] = __fmul_rn(v[j], v[j]);
    // numpy pairwise n=8: ((s0+s1)+(s2+s3)) + ((s4+s5)+(s6+s7))
    const float Aterm = __fadd_rn(
        __fadd_rn(__fadd_rn(s[0], s[1]), __fadd_rn(s[2], s[3])),
        __fadd_rn(__fadd_rn(s[4], s[5]), __fadd_rn(s[6], s[7])));
    float best = 3.4e38f; int bi = 0;
    for (int n = 0; n < NEC; ++n) {
        float4 e0 = *reinterpret_cast<const float4*>(&Es[n][0]);
        float4 e1 = *reinterpret_cast<const float4*>(&Es[n][4]);
        float bsum = __fmul_rn(v[0], e0.x);
        bsum = fmaf(v[1], e0.y, bsum);
        bsum = fmaf(v[2], e0.z, bsum);
        bsum = fmaf(v[3], e0.w, bsum);
        bsum = fmaf(v[4], e1.x, bsum);
        bsum = fmaf(v[5], e1.y, bsum);
        bsum = fmaf(v[6], e1.z, bsum);
        bsum = fmaf(v[7], e1.w, bsum);
        float d = __fadd_rn(__fsub_rn(Aterm, __fadd_rn(bsum, bsum)), Cn[n]);
        if (d < best) { best = d; bi = n; }
    }
    float4 q0 = *reinterpret_cast<const float4*>(&Es[bi][0]);
    float4 q1 = *reinterpret_cast<const float4*>(&Es[bi][4]);
    float bq[8] = {q0.x, q0.y, q0.z, q0.w, q1.x, q1.y, q1.z, q1.w};
    double dsum = 0.0;
    float* qb = qx + (size_t)b * F + c;
    #pragma unroll
    for (int j = 0; j < 8; ++j) {
        float df = __fsub_rn(bq[j], v[j]);        // fl(q - x)
        dsum += (double)df * (double)df;
        qb[j * 64] = __fadd_rn(v[j], df);         // fl(x + fl(q - x))
    }
    dsum = wave_reduce_add(dsum);
    if ((t & 63) == 0) atomicAdd(dacc, dsum);
}

// ---------------- weight quantization: dim-16 VQ (round-4 exact) ----------------
__global__ __launch_bounds__(256) void k_wq_np(
    const float* __restrict__ W2, const float* __restrict__ E,
    float* __restrict__ qW2, double* __restrict__ dacc)
{
    __shared__ float Es[NEC][16];
    __shared__ float Cn[NEC];
    const int t = threadIdx.x;
    for (int i = t; i < 16 * NEC; i += 256) Es[i & (NEC - 1)][i >> 9] = E[i];
    __syncthreads();
    for (int n = t; n < NEC; n += 256) {
        float c = __fmul_rn(Es[n][0], Es[n][0]);
        #pragma unroll
        for (int j = 1; j < 16; ++j)
            c = __fadd_rn(c, __fmul_rn(Es[n][j], Es[n][j]));
        Cn[n] = c;
    }
    __syncthreads();
    const int idx = blockIdx.x * 256 + t;   // 16384 vectors
    const int g = idx >> 6, c = idx & 63;
    float v[16];
    #pragma unroll
    for (int k = 0; k < 16; ++k)
        v[k] = W2[(size_t)(2 * g + (k & 1)) * F + 8 * c + (k >> 1)];
    float s[16];
    #pragma unroll
    for (int k = 0; k < 16; ++k) s[k] = __fmul_rn(v[k], v[k]);
    float r[8];
    #pragma unroll
    for (int j = 0; j < 8; ++j) r[j] = __fadd_rn(s[j], s[j + 8]);
    const float Aterm = __fadd_rn(
        __fadd_rn(__fadd_rn(r[0], r[1]), __fadd_rn(r[2], r[3])),
        __fadd_rn(__fadd_rn(r[4], r[5]), __fadd_rn(r[6], r[7])));
    float best = 3.4e38f; int bi = 0;
    for (int n = 0; n < NEC; ++n) {
        float bsum = __fmul_rn(v[0], Es[n][0]);
        #pragma unroll
        for (int k = 1; k < 16; ++k) bsum = fmaf(v[k], Es[n][k], bsum);
        float d = __fadd_rn(__fsub_rn(Aterm, __fadd_rn(bsum, bsum)), Cn[n]);
        if (d < best) { best = d; bi = n; }
    }
    double dsum = 0.0;
    #pragma unroll
    for (int k = 0; k < 16; ++k) {
        float df = __fsub_rn(Es[bi][k], v[k]);
        dsum += (double)df * (double)df;
        qW2[(size_t)(2 * g + (k & 1)) * F + 8 * c + (k >> 1)] = __fadd_rn(v[k], df);
    }
    dsum = wave_reduce_add(dsum);
    if ((t & 63) == 0) atomicAdd(dacc, dsum);
}

// ---------------- BN stats: numpy sequential fp32 over rows ----------------
__global__ void k_bn(const float* __restrict__ qx, float* __restrict__ mu, float* __restrict__ rs)
{
    int f = blockIdx.x * blockDim.x + threadIdx.x;
    if (f >= F) return;
    float acc = 0.f;
    for (int r = 0; r < BATCH; ++r) acc = __fadd_rn(acc, qx[(size_t)r * F + f]);
    float m = __fmul_rn(acc, 1.f / 4096.f);   // exact (/2^12)
    float acc2 = 0.f;
    for (int r = 0; r < BATCH; ++r) {
        float d = __fsub_rn(qx[(size_t)r * F + f], m);
        acc2 = __fadd_rn(acc2, __fmul_rn(d, d));
    }
    float var = __fmul_rn(acc2, 1.f / 4096.f);
    float w = __fadd_rn(var, 1e-5f);
    mu[f] = m;
    rs[f] = __fdiv_rn(1.0f, __fsqrt_rn(w));
}

// ---------------- fq22: dim-2 VQ via spatial-grid pruned search ----------------
__global__ __launch_bounds__(256) void k_fq22_np(
    const float* __restrict__ h2, const float* __restrict__ ecb3,
    const int* __restrict__ gcnt, const short* __restrict__ glist,
    float* __restrict__ qx2, double* __restrict__ dacc)
{
    __shared__ float4 EsL[NEC];
    const int t = threadIdx.x;
    for (int n = t; n < NEC; n += 256)
        EsL[n] = reinterpret_cast<const float4*>(ecb3)[n];
    __syncthreads();
    const int b = blockIdx.x;
    const float v0 = h2[(size_t)b * F + t];         // >= 0 (relu)
    const float v1 = h2[(size_t)b * F + 256 + t];   // >= 0
    const float Aterm = __fadd_rn(__fmul_rn(v0, v0), __fmul_rn(v1, v1));
    float best = 3.4e38f; int bi = 0;
    const bool inbox = (v0 < 16.f) && (v1 < 16.f);
    int cx = (int)(v0 * 4.f), cy = (int)(v1 * 4.f);
    int cell = (cy << 6) + cx;
    int cnt = inbox ? gcnt[cell] : (NEC + 1);       // out-of-box -> full scan
    if (cnt <= GCAP) {
        const short* lst = glist + (size_t)cell * GCAP;
        for (int i = 0; i < cnt; ++i) {
            int id = lst[i];                         // ids ascending -> first-min = np
            float4 e = EsL[id];
            float bsum = fmaf(v1, e.y, __fmul_rn(v0, e.x));
            float d = __fadd_rn(__fsub_rn(Aterm, __fadd_rn(bsum, bsum)), e.z);
            if (d < best) { best = d; bi = id; }
        }
    } else {
        for (int n = 0; n < NEC; ++n) {
            float4 e = EsL[n];
            float bsum = fmaf(v1, e.y, __fmul_rn(v0, e.x));
            float d = __fadd_rn(__fsub_rn(Aterm, __fadd_rn(bsum, bsum)), e.z);
            if (d < best) { best = d; bi = n; }
        }
    }
    float4 eb = EsL[bi];
    float d0 = __fsub_rn(eb.x, v0), d1 = __fsub_rn(eb.y, v1);
    qx2[(size_t)b * F + t]       = __fadd_rn(v0, d0);
    qx2[(size_t)b * F + 256 + t] = __fadd_rn(v1, d1);
    double dsum = (double)d0 * d0 + (double)d1 * d1;
    dsum = wave_reduce_add(dsum);
    if ((t & 63) == 0) atomicAdd(dacc, dsum);
}

// ---------------- final thin GEMM: out[b,o] = sum_i qx2[b,i] * W3[o,i] ----------------
__global__ __launch_bounds__(256) void k_gemm3(
    const float* __restrict__ qx2, const float* __restrict__ W3, float* __restrict__ out)
{
    __shared__ float Ws[10 * F];
    const int t = threadIdx.x;
    for (int i = t; i < 10 * F; i += 256) Ws[i] = W3[i];
    __syncthreads();
    const int w = t >> 6, l = t & 63;
    const int b = blockIdx.x * 4 + w;
    const float* xb = qx2 + (size_t)b * F;
    double acc[10] = {};
    for (int i = l; i < F; i += 64) {
        double xv = (double)xb[i];
        #pragma unroll
        for (int o = 0; o < 10; ++o) acc[o] = fma(xv, (double)Ws[o * F + i], acc[o]);
    }
    #pragma unroll
    for (int o = 0; o < 10; ++o) {
        double a = wave_reduce_add(acc[o]);
        if (l == 0) out[(size_t)b * 10 + o] = (float)a;
    }
}

// ---------------- diff scalar ----------------
__global__ void k_findiff(const double* __restrict__ dacc, float* __restrict__ out)
{
    if (threadIdx.x == 0) {
        double d21 = dacc[0] * (1.0 / 2097152.0);   // 4096*64*8
        double dq  = dacc[1] * (1.0 / 262144.0);    // 256*64*16
        double d22 = dacc[2] * (1.0 / 2097152.0);   // 4096*256*2
        out[BATCH * 10] = (float)((d21 + d22) + dq);
    }
}

extern "C" void kernel_launch(void* const* d_in, const int* in_sizes, int n_in,
                              void* d_out, int out_size, void* d_ws, size_t ws_size,
                              hipStream_t stream)
{
    const float* x     = (const float*)d_in[0];
    const float* W1    = (const float*)d_in[1];
    const float* W2    = (const float*)d_in[2];
    const float* W3    = (const float*)d_in[3];
    const float* gamma = (const float*)d_in[4];
    const float* beta  = (const float*)d_in[5];
    const float* E1    = (const float*)d_in[6];   // [8,512]
    const float* E2    = (const float*)d_in[7];   // [16,512]
    const float* E3    = (const float*)d_in[8];   // [2,512]
    float* out = (float*)d_out;

    const int KC = 512;   // confirmed round 4 (BLIS/zen single-panel for K=512)

    char* ws = (char*)d_ws;
    float*  hf    = (float*)ws;                                 // 8 MB (h, then h2)
    float*  qxf   = (float*)(ws + (size_t) 8 * 1024 * 1024);    // 8 MB (qx, then qx2)
    float*  qW2f  = (float*)(ws + (size_t)16 * 1024 * 1024);    // 1 MB
    float*  muf   = (float*)(ws + (size_t)17 * 1024 * 1024);    // 512 f32
    float*  rsf   = muf + F;                                    // 512 f32
    double* dacc  = (double*)(ws + (size_t)17 * 1024 * 1024 + 4096);   // 3 doubles
    float*  ecb3  = (float*)(ws + (size_t)17 * 1024 * 1024 + 8192);    // 512*4 f32
    int*    gcnt  = (int*)(ws + (size_t)18 * 1024 * 1024);      // 4096 int
    short*  glist = (short*)(ws + (size_t)18 * 1024 * 1024 + 16384);   // 4096*96 i16

    k_zero_d<<<1, 64, 0, stream>>>(dacc, 3);
    k_prep<<<8, 64, 0, stream>>>(E3, ecb3);
    k_grid<<<16, 256, 0, stream>>>(E3, gcnt, glist);
    // h = relu(x @ W1^T)  — sgemm emulation, KC panels (784 = 512 + 272)
    k_gemm_np<true, false><<<dim3(F / 64, BATCH / 64), 256, 0, stream>>>(
        x, W1, hf, BATCH, F, D_IN, KC, nullptr, nullptr, nullptr, nullptr);
    // fq21 -> qx
    k_fq21_np<<<BATCH * 64 / 256, 256, 0, stream>>>(hf, E1, qxf, dacc + 0);
    // weight quantization -> qW2
    k_wq_np<<<64, 256, 0, stream>>>(W2, E2, qW2f, dacc + 1);
    // BN stats (sequential fp32, numpy order)
    k_bn<<<2, 256, 0, stream>>>(qxf, muf, rsf);
    // h2 = relu(bn(qx) @ qW2^T) — K=512 = single panel -> pure sequential fma
    k_gemm_np<true, true><<<dim3(F / 64, BATCH / 64), 256, 0, stream>>>(
        qxf, qW2f, hf, BATCH, F, F, KC, muf, rsf, gamma, beta);
    // fq22 -> qx2 (grid-pruned)
    k_fq22_np<<<BATCH, 256, 0, stream>>>(hf, ecb3, gcnt, glist, qxf, dacc + 2);
    // out = qx2 @ W3^T
    k_gemm3<<<BATCH / 4, 256, 0, stream>>>(qxf, W3, out);
    k_findiff<<<1, 64, 0, stream>>>(dacc, out);
}

// Round 7
// 615.632 us; speedup vs baseline: 1.2178x; 1.1938x over previous
//
#include <hip/hip_runtime.h>
#include <math.h>

constexpr int BATCH = 4096;
constexpr int D_IN  = 784;
constexpr int F     = 512;
constexpr int NEC   = 512;   // codebook entries

constexpr int   GRID_N = 64;     // fq22 spatial grid
constexpr float GCELL  = 0.25f;  // covers [0,16) x [0,16)
constexpr int   GCAP   = 96;     // max candidates per cell

// ---------------- zero init (doubles) ----------------
__global__ void k_zero_d(double* p, int n) {
    int i = blockIdx.x * blockDim.x + threadIdx.x;
    if (i < n) p[i] = 0.0;
}

// ---------------- prep: pack fq22 codebook {e0,e1,|e|^2,0} ----------------
__global__ void k_prep(const float* __restrict__ E3, float* __restrict__ ecb3)
{
    int n = blockIdx.x * 64 + threadIdx.x;
    if (n >= NEC) return;
    float a0 = E3[n], a1 = E3[NEC + n];
    float cn = __fadd_rn(__fmul_rn(a0, a0), __fmul_rn(a1, a1));
    reinterpret_cast<float4*>(ecb3)[n] = make_float4(a0, a1, cn, 0.f);
}

// ---------------- fq22 grid build: one thread per cell ----------------
__global__ void k_grid(const float* __restrict__ E3,
                       int* __restrict__ gcnt, short* __restrict__ glist)
{
    int cell = blockIdx.x * 256 + threadIdx.x;
    if (cell >= GRID_N * GRID_N) return;
    int cx = cell & (GRID_N - 1), cy = cell >> 6;
    float x0 = cx * GCELL, x1 = x0 + GCELL;
    float y0 = cy * GCELL, y1 = y0 + GCELL;
    float minUpper = 3.4e38f;
    for (int n = 0; n < NEC; ++n) {
        float ex = E3[n], ey = E3[NEC + n];
        float dxmax = fmaxf(x1 - ex, ex - x0);
        float dymax = fmaxf(y1 - ey, ey - y0);
        minUpper = fminf(minUpper, dxmax * dxmax + dymax * dymax);
    }
    float thr = minUpper + 0.01f;
    int cnt = 0;
    for (int n = 0; n < NEC; ++n) {
        float ex = E3[n], ey = E3[NEC + n];
        float dxmin = fmaxf(fmaxf(x0 - ex, ex - x1), 0.f);
        float dymin = fmaxf(fmaxf(y0 - ey, ey - y1), 0.f);
        if (dxmin * dxmin + dymin * dymin <= thr) {
            if (cnt < GCAP) glist[(size_t)cell * GCAP + cnt] = (short)n;
            ++cnt;
        }
    }
    gcnt[cell] = cnt;
}

// ---- GEMM (NT) emulating BLAS sgemm: per-output sequential-k fma chain
// ---- within KC-panels (runtime KC), panel partials combined in order with fp32 adds.
template<bool RELU, bool BN>
__global__ __launch_bounds__(256) void k_gemm_np(
    const float* __restrict__ A, const float* __restrict__ Bw, float* __restrict__ C,
    int M, int N, int K, int KC,
    const float* __restrict__ mu, const float* __restrict__ rs,
    const float* __restrict__ gamma, const float* __restrict__ beta)
{
    __shared__ float As[16][68];
    __shared__ float Bs[16][68];
    const int t  = threadIdx.x;
    const int bm = blockIdx.y * 64, bn = blockIdx.x * 64;
    const int tm = (t >> 4) * 4, tn = (t & 15) * 4;
    const int rA = t >> 2;
    const int c4 = (t & 3) * 4;
    const float* Arow = A + (size_t)(bm + rA) * K;
    const float* Brow = Bw + (size_t)(bn + rA) * K;
    float tot[4][4];
    float accp[4][4] = {};
    bool first = true;
    for (int k0 = 0; k0 < K; k0 += 16) {
        float4 af = *reinterpret_cast<const float4*>(Arow + k0 + c4);
        float4 bf = *reinterpret_cast<const float4*>(Brow + k0 + c4);
        float av[4] = {af.x, af.y, af.z, af.w};
        if (BN) {
            #pragma unroll
            for (int u = 0; u < 4; ++u) {
                const int k = k0 + c4 + u;
                float d = __fsub_rn(av[u], mu[k]);
                d = __fmul_rn(d, rs[k]);
                d = __fmul_rn(d, gamma[k]);
                av[u] = __fadd_rn(d, beta[k]);
            }
        }
        As[c4 + 0][rA] = av[0]; As[c4 + 1][rA] = av[1];
        As[c4 + 2][rA] = av[2]; As[c4 + 3][rA] = av[3];
        Bs[c4 + 0][rA] = bf.x;  Bs[c4 + 1][rA] = bf.y;
        Bs[c4 + 2][rA] = bf.z;  Bs[c4 + 3][rA] = bf.w;
        __syncthreads();
        #pragma unroll
        for (int kk = 0; kk < 16; ++kk) {
            float4 a4 = *reinterpret_cast<const float4*>(&As[kk][tm]);
            float4 b4 = *reinterpret_cast<const float4*>(&Bs[kk][tn]);
            float aa[4] = {a4.x, a4.y, a4.z, a4.w};
            float bb[4] = {b4.x, b4.y, b4.z, b4.w};
            #pragma unroll
            for (int i = 0; i < 4; ++i)
                #pragma unroll
                for (int j = 0; j < 4; ++j)
                    accp[i][j] = fmaf(aa[i], bb[j], accp[i][j]);
        }
        __syncthreads();
        const int kend = k0 + 16;
        if ((kend % KC) == 0 || kend == K) {   // panel boundary: fold partial
            #pragma unroll
            for (int i = 0; i < 4; ++i)
                #pragma unroll
                for (int j = 0; j < 4; ++j) {
                    tot[i][j] = first ? accp[i][j] : __fadd_rn(tot[i][j], accp[i][j]);
                    accp[i][j] = 0.f;
                }
            first = false;
        }
    }
    #pragma unroll
    for (int i = 0; i < 4; ++i) {
        float r0 = RELU ? fmaxf(tot[i][0], 0.f) : tot[i][0];
        float r1 = RELU ? fmaxf(tot[i][1], 0.f) : tot[i][1];
        float r2 = RELU ? fmaxf(tot[i][2], 0.f) : tot[i][2];
        float r3 = RELU ? fmaxf(tot[i][3], 0.f) : tot[i][3];
        float4 r = make_float4(r0, r1, r2, r3);
        *reinterpret_cast<float4*>(&C[(size_t)(bm + tm + i) * N + bn + tn]) = r;
    }
}

// ---------------- wave reduce helper (fp64) ----------------
__device__ __forceinline__ double wave_reduce_add(double v) {
    #pragma unroll
    for (int off = 32; off; off >>= 1) v += __shfl_xor(v, off);
    return v;
}

// ---------------- fq21: dim-8 VQ, LDS codebook, index-only tracking ----------------
__global__ __launch_bounds__(256) void k_fq21_np(
    const float* __restrict__ h, const float* __restrict__ E,
    float* __restrict__ qx, double* __restrict__ dacc)
{
    __shared__ float Es[NEC][8];
    __shared__ float Cn[NEC];
    const int t = threadIdx.x;
    for (int i = t; i < 8 * NEC; i += 256) Es[i & (NEC - 1)][i >> 9] = E[i];
    __syncthreads();
    for (int n = t; n < NEC; n += 256) {
        float c = __fmul_rn(Es[n][0], Es[n][0]);
        #pragma unroll
        for (int j = 1; j < 8; ++j)
            c = __fadd_rn(c, __fmul_rn(Es[n][j], Es[n][j]));
        Cn[n] = c;
    }
    __syncthreads();
    const int idx = blockIdx.x * 256 + t;
    const int b = idx >> 6, c = idx & 63;
    const float* hb = h + (size_t)b * F + c;
    float v[8];
    #pragma unroll
    for (int j = 0; j < 8; ++j) v[j] = hb[j * 64];
    float s[8];
    #pragma unroll
    for (int j = 0; j < 8; ++j) s[j] = __fmul_rn(v[j], v[j]);
    // numpy pairwise n=8: ((s0+s1)+(s2+s3)) + ((s4+s5)+(s6+s7))
    const float Aterm = __fadd_rn(
        __fadd_rn(__fadd_rn(s[0], s[1]), __fadd_rn(s[2], s[3])),
        __fadd_rn(__fadd_rn(s[4], s[5]), __fadd_rn(s[6], s[7])));
    float best = 3.4e38f; int bi = 0;
    for (int n = 0; n < NEC; ++n) {
        float4 e0 = *reinterpret_cast<const float4*>(&Es[n][0]);
        float4 e1 = *reinterpret_cast<const float4*>(&Es[n][4]);
        float bsum = __fmul_rn(v[0], e0.x);
        bsum = fmaf(v[1], e0.y, bsum);
        bsum = fmaf(v[2], e0.z, bsum);
        bsum = fmaf(v[3], e0.w, bsum);
        bsum = fmaf(v[4], e1.x, bsum);
        bsum = fmaf(v[5], e1.y, bsum);
        bsum = fmaf(v[6], e1.z, bsum);
        bsum = fmaf(v[7], e1.w, bsum);
        float d = __fadd_rn(__fsub_rn(Aterm, __fadd_rn(bsum, bsum)), Cn[n]);
        if (d < best) { best = d; bi = n; }
    }
    float4 q0 = *reinterpret_cast<const float4*>(&Es[bi][0]);
    float4 q1 = *reinterpret_cast<const float4*>(&Es[bi][4]);
    float bq[8] = {q0.x, q0.y, q0.z, q0.w, q1.x, q1.y, q1.z, q1.w};
    double dsum = 0.0;
    float* qb = qx + (size_t)b * F + c;
    #pragma unroll
    for (int j = 0; j < 8; ++j) {
        float df = __fsub_rn(bq[j], v[j]);        // fl(q - x)
        dsum += (double)df * (double)df;
        qb[j * 64] = __fadd_rn(v[j], df);         // fl(x + fl(q - x))
    }
    dsum = wave_reduce_add(dsum);
    if ((t & 63) == 0) atomicAdd(dacc, dsum);
}

// ---------------- weight quantization: dim-16 VQ (round-4 exact) ----------------
__global__ __launch_bounds__(256) void k_wq_np(
    const float* __restrict__ W2, const float* __restrict__ E,
    float* __restrict__ qW2, double* __restrict__ dacc)
{
    __shared__ float Es[NEC][16];
    __shared__ float Cn[NEC];
    const int t = threadIdx.x;
    for (int i = t; i < 16 * NEC; i += 256) Es[i & (NEC - 1)][i >> 9] = E[i];
    __syncthreads();
    for (int n = t; n < NEC; n += 256) {
        float c = __fmul_rn(Es[n][0], Es[n][0]);
        #pragma unroll
        for (int j = 1; j < 16; ++j)
            c = __fadd_rn(c, __fmul_rn(Es[n][j], Es[n][j]));
        Cn[n] = c;
    }
    __syncthreads();
    const int idx = blockIdx.x * 256 + t;   // 16384 vectors
    const int g = idx >> 6, c = idx & 63;
    float v[16];
    #pragma unroll
    for (int k = 0; k < 16; ++k)
        v[k] = W2[(size_t)(2 * g + (k & 1)) * F + 8 * c + (k >> 1)];
    float s[16];
    #pragma unroll
    for (int k = 0; k < 16; ++k) s[k] = __fmul_rn(v[k], v[k]);
    float r[8];
    #pragma unroll
    for (int j = 0; j < 8; ++j) r[j] = __fadd_rn(s[j], s[j + 8]);
    const float Aterm = __fadd_rn(
        __fadd_rn(__fadd_rn(r[0], r[1]), __fadd_rn(r[2], r[3])),
        __fadd_rn(__fadd_rn(r[4], r[5]), __fadd_rn(r[6], r[7])));
    float best = 3.4e38f; int bi = 0;
    for (int n = 0; n < NEC; ++n) {
        float bsum = __fmul_rn(v[0], Es[n][0]);
        #pragma unroll
        for (int k = 1; k < 16; ++k) bsum = fmaf(v[k], Es[n][k], bsum);
        float d = __fadd_rn(__fsub_rn(Aterm, __fadd_rn(bsum, bsum)), Cn[n]);
        if (d < best) { best = d; bi = n; }
    }
    double dsum = 0.0;
    #pragma unroll
    for (int k = 0; k < 16; ++k) {
        float df = __fsub_rn(Es[bi][k], v[k]);
        dsum += (double)df * (double)df;
        qW2[(size_t)(2 * g + (k & 1)) * F + 8 * c + (k >> 1)] = __fadd_rn(v[k], df);
    }
    dsum = wave_reduce_add(dsum);
    if ((t & 63) == 0) atomicAdd(dacc, dsum);
}

// ---------------- BN stats: numpy sequential fp32, double-buffered loads ----------------
// One thread per column. The add chain stays in exact numpy row order; loads for
// the next 16-row batch are issued while the current batch's adds retire
// (two NAMED register arrays -> static indexing, no scratch).
__global__ __launch_bounds__(64) void k_bn(
    const float* __restrict__ qx, float* __restrict__ mu, float* __restrict__ rs)
{
    const int f = blockIdx.x * 64 + threadIdx.x;   // 8 blocks x 64 threads = 512 cols
    const float* col = qx + f;

    float bufA[16], bufB[16];
    // ---- pass 1: mean ----
    #pragma unroll
    for (int j = 0; j < 16; ++j) bufA[j] = col[(size_t)j * F];
    float acc = 0.f;
    for (int b = 0; b < 128; ++b) {            // 128 iters x 32 rows
        const int base = b * 32;
        #pragma unroll
        for (int j = 0; j < 16; ++j) bufB[j] = col[(size_t)(base + 16 + j) * F];
        #pragma unroll
        for (int j = 0; j < 16; ++j) acc = __fadd_rn(acc, bufA[j]);
        if (b < 127) {
            #pragma unroll
            for (int j = 0; j < 16; ++j) bufA[j] = col[(size_t)(base + 32 + j) * F];
        }
        #pragma unroll
        for (int j = 0; j < 16; ++j) acc = __fadd_rn(acc, bufB[j]);
    }
    const float m = __fmul_rn(acc, 1.f / 4096.f);   // exact (/2^12)

    // ---- pass 2: biased var, numpy order ----
    #pragma unroll
    for (int j = 0; j < 16; ++j) bufA[j] = col[(size_t)j * F];
    float acc2 = 0.f;
    for (int b = 0; b < 128; ++b) {
        const int base = b * 32;
        #pragma unroll
        for (int j = 0; j < 16; ++j) bufB[j] = col[(size_t)(base + 16 + j) * F];
        #pragma unroll
        for (int j = 0; j < 16; ++j) {
            float d = __fsub_rn(bufA[j], m);
            acc2 = __fadd_rn(acc2, __fmul_rn(d, d));
        }
        if (b < 127) {
            #pragma unroll
            for (int j = 0; j < 16; ++j) bufA[j] = col[(size_t)(base + 32 + j) * F];
        }
        #pragma unroll
        for (int j = 0; j < 16; ++j) {
            float d = __fsub_rn(bufB[j], m);
            acc2 = __fadd_rn(acc2, __fmul_rn(d, d));
        }
    }
    float var = __fmul_rn(acc2, 1.f / 4096.f);
    float w = __fadd_rn(var, 1e-5f);
    mu[f] = m;
    rs[f] = __fdiv_rn(1.0f, __fsqrt_rn(w));
}

// ---------------- fq22: dim-2 VQ via spatial-grid pruned search ----------------
__global__ __launch_bounds__(256) void k_fq22_np(
    const float* __restrict__ h2, const float* __restrict__ ecb3,
    const int* __restrict__ gcnt, const short* __restrict__ glist,
    float* __restrict__ qx2, double* __restrict__ dacc)
{
    __shared__ float4 EsL[NEC];
    const int t = threadIdx.x;
    for (int n = t; n < NEC; n += 256)
        EsL[n] = reinterpret_cast<const float4*>(ecb3)[n];
    __syncthreads();
    const int b = blockIdx.x;
    const float v0 = h2[(size_t)b * F + t];         // >= 0 (relu)
    const float v1 = h2[(size_t)b * F + 256 + t];   // >= 0
    const float Aterm = __fadd_rn(__fmul_rn(v0, v0), __fmul_rn(v1, v1));
    float best = 3.4e38f; int bi = 0;
    const bool inbox = (v0 < 16.f) && (v1 < 16.f);
    int cx = (int)(v0 * 4.f), cy = (int)(v1 * 4.f);
    int cell = (cy << 6) + cx;
    int cnt = inbox ? gcnt[cell] : (NEC + 1);       // out-of-box -> full scan
    if (cnt <= GCAP) {
        const short* lst = glist + (size_t)cell * GCAP;
        for (int i = 0; i < cnt; ++i) {
            int id = lst[i];                         // ids ascending -> first-min = np
            float4 e = EsL[id];
            float bsum = fmaf(v1, e.y, __fmul_rn(v0, e.x));
            float d = __fadd_rn(__fsub_rn(Aterm, __fadd_rn(bsum, bsum)), e.z);
            if (d < best) { best = d; bi = id; }
        }
    } else {
        for (int n = 0; n < NEC; ++n) {
            float4 e = EsL[n];
            float bsum = fmaf(v1, e.y, __fmul_rn(v0, e.x));
            float d = __fadd_rn(__fsub_rn(Aterm, __fadd_rn(bsum, bsum)), e.z);
            if (d < best) { best = d; bi = n; }
        }
    }
    float4 eb = EsL[bi];
    float d0 = __fsub_rn(eb.x, v0), d1 = __fsub_rn(eb.y, v1);
    qx2[(size_t)b * F + t]       = __fadd_rn(v0, d0);
    qx2[(size_t)b * F + 256 + t] = __fadd_rn(v1, d1);
    double dsum = (double)d0 * d0 + (double)d1 * d1;
    dsum = wave_reduce_add(dsum);
    if ((t & 63) == 0) atomicAdd(dacc, dsum);
}

// ---------------- final thin GEMM: out[b,o] = sum_i qx2[b,i] * W3[o,i] ----------------
__global__ __launch_bounds__(256) void k_gemm3(
    const float* __restrict__ qx2, const float* __restrict__ W3, float* __restrict__ out)
{
    __shared__ float Ws[10 * F];
    const int t = threadIdx.x;
    for (int i = t; i < 10 * F; i += 256) Ws[i] = W3[i];
    __syncthreads();
    const int w = t >> 6, l = t & 63;
    const int b = blockIdx.x * 4 + w;
    const float* xb = qx2 + (size_t)b * F;
    double acc[10] = {};
    for (int i = l; i < F; i += 64) {
        double xv = (double)xb[i];
        #pragma unroll
        for (int o = 0; o < 10; ++o) acc[o] = fma(xv, (double)Ws[o * F + i], acc[o]);
    }
    #pragma unroll
    for (int o = 0; o < 10; ++o) {
        double a = wave_reduce_add(acc[o]);
        if (l == 0) out[(size_t)b * 10 + o] = (float)a;
    }
}

// ---------------- diff scalar ----------------
__global__ void k_findiff(const double* __restrict__ dacc, float* __restrict__ out)
{
    if (threadIdx.x == 0) {
        double d21 = dacc[0] * (1.0 / 2097152.0);   // 4096*64*8
        double dq  = dacc[1] * (1.0 / 262144.0);    // 256*64*16
        double d22 = dacc[2] * (1.0 / 2097152.0);   // 4096*256*2
        out[BATCH * 10] = (float)((d21 + d22) + dq);
    }
}

extern "C" void kernel_launch(void* const* d_in, const int* in_sizes, int n_in,
                              void* d_out, int out_size, void* d_ws, size_t ws_size,
                              hipStream_t stream)
{
    const float* x     = (const float*)d_in[0];
    const float* W1    = (const float*)d_in[1];
    const float* W2    = (const float*)d_in[2];
    const float* W3    = (const float*)d_in[3];
    const float* gamma = (const float*)d_in[4];
    const float* beta  = (const float*)d_in[5];
    const float* E1    = (const float*)d_in[6];   // [8,512]
    const float* E2    = (const float*)d_in[7];   // [16,512]
    const float* E3    = (const float*)d_in[8];   // [2,512]
    float* out = (float*)d_out;

    const int KC = 512;   // confirmed round 4 (BLIS/zen single-panel for K=512)

    char* ws = (char*)d_ws;
    float*  hf    = (float*)ws;                                 // 8 MB (h, then h2)
    float*  qxf   = (float*)(ws + (size_t) 8 * 1024 * 1024);    // 8 MB (qx, then qx2)
    float*  qW2f  = (float*)(ws + (size_t)16 * 1024 * 1024);    // 1 MB
    float*  muf   = (float*)(ws + (size_t)17 * 1024 * 1024);    // 512 f32
    float*  rsf   = muf + F;                                    // 512 f32
    double* dacc  = (double*)(ws + (size_t)17 * 1024 * 1024 + 4096);   // 3 doubles
    float*  ecb3  = (float*)(ws + (size_t)17 * 1024 * 1024 + 8192);    // 512*4 f32
    int*    gcnt  = (int*)(ws + (size_t)18 * 1024 * 1024);      // 4096 int
    short*  glist = (short*)(ws + (size_t)18 * 1024 * 1024 + 16384);   // 4096*96 i16

    k_zero_d<<<1, 64, 0, stream>>>(dacc, 3);
    k_prep<<<8, 64, 0, stream>>>(E3, ecb3);
    k_grid<<<16, 256, 0, stream>>>(E3, gcnt, glist);
    // h = relu(x @ W1^T)  — sgemm emulation, KC panels (784 = 512 + 272)
    k_gemm_np<true, false><<<dim3(F / 64, BATCH / 64), 256, 0, stream>>>(
        x, W1, hf, BATCH, F, D_IN, KC, nullptr, nullptr, nullptr, nullptr);
    // fq21 -> qx
    k_fq21_np<<<BATCH * 64 / 256, 256, 0, stream>>>(hf, E1, qxf, dacc + 0);
    // weight quantization -> qW2
    k_wq_np<<<64, 256, 0, stream>>>(W2, E2, qW2f, dacc + 1);
    // BN stats (sequential fp32, numpy order; latency-hidden)
    k_bn<<<8, 64, 0, stream>>>(qxf, muf, rsf);
    // h2 = relu(bn(qx) @ qW2^T) — K=512 = single panel -> pure sequential fma
    k_gemm_np<true, true><<<dim3(F / 64, BATCH / 64), 256, 0, stream>>>(
        qxf, qW2f, hf, BATCH, F, F, KC, muf, rsf, gamma, beta);
    // fq22 -> qx2 (grid-pruned)
    k_fq22_np<<<BATCH, 256, 0, stream>>>(hf, ecb3, gcnt, glist, qxf, dacc + 2);
    // out = qx2 @ W3^T
    k_gemm3<<<BATCH / 4, 256, 0, stream>>>(qxf, W3, out);
    k_findiff<<<1, 64, 0, stream>>>(dacc, out);
}

// Round 8
// 404.288 us; speedup vs baseline: 1.8545x; 1.5228x over previous
//
#include <hip/hip_runtime.h>
#include <math.h>

constexpr int BATCH = 4096;
constexpr int D_IN  = 784;
constexpr int F     = 512;
constexpr int NEC   = 512;   // codebook entries

constexpr int   GRID_N = 64;     // fq22 spatial grid
constexpr float GCELL  = 0.25f;  // covers [0,16) x [0,16)
constexpr int   GCAP   = 96;     // max candidates per cell

// ---------------- prep: pack fq22 codebook {e0,e1,|e|^2,0} ----------------
__global__ void k_prep(const float* __restrict__ E3, float* __restrict__ ecb3)
{
    int n = blockIdx.x * 64 + threadIdx.x;
    if (n >= NEC) return;
    float a0 = E3[n], a1 = E3[NEC + n];
    float cn = __fadd_rn(__fmul_rn(a0, a0), __fmul_rn(a1, a1));
    reinterpret_cast<float4*>(ecb3)[n] = make_float4(a0, a1, cn, 0.f);
}

// ---------------- fq22 grid build: one thread per cell ----------------
__global__ void k_grid(const float* __restrict__ E3,
                       int* __restrict__ gcnt, short* __restrict__ glist)
{
    int cell = blockIdx.x * 256 + threadIdx.x;
    if (cell >= GRID_N * GRID_N) return;
    int cx = cell & (GRID_N - 1), cy = cell >> 6;
    float x0 = cx * GCELL, x1 = x0 + GCELL;
    float y0 = cy * GCELL, y1 = y0 + GCELL;
    float minUpper = 3.4e38f;
    for (int n = 0; n < NEC; ++n) {
        float ex = E3[n], ey = E3[NEC + n];
        float dxmax = fmaxf(x1 - ex, ex - x0);
        float dymax = fmaxf(y1 - ey, ey - y0);
        minUpper = fminf(minUpper, dxmax * dxmax + dymax * dymax);
    }
    float thr = minUpper + 0.01f;
    int cnt = 0;
    for (int n = 0; n < NEC; ++n) {
        float ex = E3[n], ey = E3[NEC + n];
        float dxmin = fmaxf(fmaxf(x0 - ex, ex - x1), 0.f);
        float dymin = fmaxf(fmaxf(y0 - ey, ey - y1), 0.f);
        if (dxmin * dxmin + dymin * dymin <= thr) {
            if (cnt < GCAP) glist[(size_t)cell * GCAP + cnt] = (short)n;
            ++cnt;
        }
    }
    gcnt[cell] = cnt;
}

// ---- GEMM (NT) emulating BLAS sgemm: per-output sequential-k fma chain
// ---- within KC-panels (runtime KC), panel partials combined in order with fp32 adds.
template<bool RELU, bool BN>
__global__ __launch_bounds__(256) void k_gemm_np(
    const float* __restrict__ A, const float* __restrict__ Bw, float* __restrict__ C,
    int M, int N, int K, int KC,
    const float* __restrict__ mu, const float* __restrict__ rs,
    const float* __restrict__ gamma, const float* __restrict__ beta)
{
    __shared__ float As[16][68];
    __shared__ float Bs[16][68];
    const int t  = threadIdx.x;
    const int bm = blockIdx.y * 64, bn = blockIdx.x * 64;
    const int tm = (t >> 4) * 4, tn = (t & 15) * 4;
    const int rA = t >> 2;
    const int c4 = (t & 3) * 4;
    const float* Arow = A + (size_t)(bm + rA) * K;
    const float* Brow = Bw + (size_t)(bn + rA) * K;
    float tot[4][4];
    float accp[4][4] = {};
    bool first = true;
    for (int k0 = 0; k0 < K; k0 += 16) {
        float4 af = *reinterpret_cast<const float4*>(Arow + k0 + c4);
        float4 bf = *reinterpret_cast<const float4*>(Brow + k0 + c4);
        float av[4] = {af.x, af.y, af.z, af.w};
        if (BN) {
            #pragma unroll
            for (int u = 0; u < 4; ++u) {
                const int k = k0 + c4 + u;
                float d = __fsub_rn(av[u], mu[k]);
                d = __fmul_rn(d, rs[k]);
                d = __fmul_rn(d, gamma[k]);
                av[u] = __fadd_rn(d, beta[k]);
            }
        }
        As[c4 + 0][rA] = av[0]; As[c4 + 1][rA] = av[1];
        As[c4 + 2][rA] = av[2]; As[c4 + 3][rA] = av[3];
        Bs[c4 + 0][rA] = bf.x;  Bs[c4 + 1][rA] = bf.y;
        Bs[c4 + 2][rA] = bf.z;  Bs[c4 + 3][rA] = bf.w;
        __syncthreads();
        #pragma unroll
        for (int kk = 0; kk < 16; ++kk) {
            float4 a4 = *reinterpret_cast<const float4*>(&As[kk][tm]);
            float4 b4 = *reinterpret_cast<const float4*>(&Bs[kk][tn]);
            float aa[4] = {a4.x, a4.y, a4.z, a4.w};
            float bb[4] = {b4.x, b4.y, b4.z, b4.w};
            #pragma unroll
            for (int i = 0; i < 4; ++i)
                #pragma unroll
                for (int j = 0; j < 4; ++j)
                    accp[i][j] = fmaf(aa[i], bb[j], accp[i][j]);
        }
        __syncthreads();
        const int kend = k0 + 16;
        if ((kend % KC) == 0 || kend == K) {   // panel boundary: fold partial
            #pragma unroll
            for (int i = 0; i < 4; ++i)
                #pragma unroll
                for (int j = 0; j < 4; ++j) {
                    tot[i][j] = first ? accp[i][j] : __fadd_rn(tot[i][j], accp[i][j]);
                    accp[i][j] = 0.f;
                }
            first = false;
        }
    }
    #pragma unroll
    for (int i = 0; i < 4; ++i) {
        float r0 = RELU ? fmaxf(tot[i][0], 0.f) : tot[i][0];
        float r1 = RELU ? fmaxf(tot[i][1], 0.f) : tot[i][1];
        float r2 = RELU ? fmaxf(tot[i][2], 0.f) : tot[i][2];
        float r3 = RELU ? fmaxf(tot[i][3], 0.f) : tot[i][3];
        float4 r = make_float4(r0, r1, r2, r3);
        *reinterpret_cast<float4*>(&C[(size_t)(bm + tm + i) * N + bn + tn]) = r;
    }
}

// ---------------- wave reduce + block partial helpers (no atomics) ----------------
__device__ __forceinline__ double wave_reduce_add(double v) {
    #pragma unroll
    for (int off = 32; off; off >>= 1) v += __shfl_xor(v, off);
    return v;
}

// 4-wave block: fixed-order fp64 partial -> pbuf[blockIdx.x]
__device__ __forceinline__ void block_partial(double dsum, double* pbuf) {
    __shared__ double wsum[4];
    const int t = threadIdx.x;
    dsum = wave_reduce_add(dsum);
    if ((t & 63) == 0) wsum[t >> 6] = dsum;
    __syncthreads();
    if (t == 0)
        pbuf[blockIdx.x] = ((wsum[0] + wsum[1]) + wsum[2]) + wsum[3];
}

// ---------------- fq21: dim-8 VQ, LDS codebook, index-only tracking ----------------
__global__ __launch_bounds__(256) void k_fq21_np(
    const float* __restrict__ h, const float* __restrict__ E,
    float* __restrict__ qx, double* __restrict__ pbuf)
{
    __shared__ float Es[NEC][8];
    __shared__ float Cn[NEC];
    const int t = threadIdx.x;
    for (int i = t; i < 8 * NEC; i += 256) Es[i & (NEC - 1)][i >> 9] = E[i];
    __syncthreads();
    for (int n = t; n < NEC; n += 256) {
        float c = __fmul_rn(Es[n][0], Es[n][0]);
        #pragma unroll
        for (int j = 1; j < 8; ++j)
            c = __fadd_rn(c, __fmul_rn(Es[n][j], Es[n][j]));
        Cn[n] = c;
    }
    __syncthreads();
    const int idx = blockIdx.x * 256 + t;
    const int b = idx >> 6, c = idx & 63;
    const float* hb = h + (size_t)b * F + c;
    float v[8];
    #pragma unroll
    for (int j = 0; j < 8; ++j) v[j] = hb[j * 64];
    float s[8];
    #pragma unroll
    for (int j = 0; j < 8; ++j) s[j] = __fmul_rn(v[j], v[j]);
    // numpy pairwise n=8: ((s0+s1)+(s2+s3)) + ((s4+s5)+(s6+s7))
    const float Aterm = __fadd_rn(
        __fadd_rn(__fadd_rn(s[0], s[1]), __fadd_rn(s[2], s[3])),
        __fadd_rn(__fadd_rn(s[4], s[5]), __fadd_rn(s[6], s[7])));
    float best = 3.4e38f; int bi = 0;
    for (int n = 0; n < NEC; ++n) {
        float4 e0 = *reinterpret_cast<const float4*>(&Es[n][0]);
        float4 e1 = *reinterpret_cast<const float4*>(&Es[n][4]);
        float bsum = __fmul_rn(v[0], e0.x);
        bsum = fmaf(v[1], e0.y, bsum);
        bsum = fmaf(v[2], e0.z, bsum);
        bsum = fmaf(v[3], e0.w, bsum);
        bsum = fmaf(v[4], e1.x, bsum);
        bsum = fmaf(v[5], e1.y, bsum);
        bsum = fmaf(v[6], e1.z, bsum);
        bsum = fmaf(v[7], e1.w, bsum);
        float d = __fadd_rn(__fsub_rn(Aterm, __fadd_rn(bsum, bsum)), Cn[n]);
        if (d < best) { best = d; bi = n; }
    }
    float4 q0 = *reinterpret_cast<const float4*>(&Es[bi][0]);
    float4 q1 = *reinterpret_cast<const float4*>(&Es[bi][4]);
    float bq[8] = {q0.x, q0.y, q0.z, q0.w, q1.x, q1.y, q1.z, q1.w};
    double dsum = 0.0;
    float* qb = qx + (size_t)b * F + c;
    #pragma unroll
    for (int j = 0; j < 8; ++j) {
        float df = __fsub_rn(bq[j], v[j]);        // fl(q - x)
        dsum += (double)df * (double)df;
        qb[j * 64] = __fadd_rn(v[j], df);         // fl(x + fl(q - x))
    }
    block_partial(dsum, pbuf);
}

// ---------------- weight quantization: dim-16 VQ (round-4 exact) ----------------
__global__ __launch_bounds__(256) void k_wq_np(
    const float* __restrict__ W2, const float* __restrict__ E,
    float* __restrict__ qW2, double* __restrict__ pbuf)
{
    __shared__ float Es[NEC][16];
    __shared__ float Cn[NEC];
    const int t = threadIdx.x;
    for (int i = t; i < 16 * NEC; i += 256) Es[i & (NEC - 1)][i >> 9] = E[i];
    __syncthreads();
    for (int n = t; n < NEC; n += 256) {
        float c = __fmul_rn(Es[n][0], Es[n][0]);
        #pragma unroll
        for (int j = 1; j < 16; ++j)
            c = __fadd_rn(c, __fmul_rn(Es[n][j], Es[n][j]));
        Cn[n] = c;
    }
    __syncthreads();
    const int idx = blockIdx.x * 256 + t;   // 16384 vectors
    const int g = idx >> 6, c = idx & 63;
    float v[16];
    #pragma unroll
    for (int k = 0; k < 16; ++k)
        v[k] = W2[(size_t)(2 * g + (k & 1)) * F + 8 * c + (k >> 1)];
    float s[16];
    #pragma unroll
    for (int k = 0; k < 16; ++k) s[k] = __fmul_rn(v[k], v[k]);
    float r[8];
    #pragma unroll
    for (int j = 0; j < 8; ++j) r[j] = __fadd_rn(s[j], s[j + 8]);
    const float Aterm = __fadd_rn(
        __fadd_rn(__fadd_rn(r[0], r[1]), __fadd_rn(r[2], r[3])),
        __fadd_rn(__fadd_rn(r[4], r[5]), __fadd_rn(r[6], r[7])));
    float best = 3.4e38f; int bi = 0;
    for (int n = 0; n < NEC; ++n) {
        float bsum = __fmul_rn(v[0], Es[n][0]);
        #pragma unroll
        for (int k = 1; k < 16; ++k) bsum = fmaf(v[k], Es[n][k], bsum);
        float d = __fadd_rn(__fsub_rn(Aterm, __fadd_rn(bsum, bsum)), Cn[n]);
        if (d < best) { best = d; bi = n; }
    }
    double dsum = 0.0;
    #pragma unroll
    for (int k = 0; k < 16; ++k) {
        float df = __fsub_rn(Es[bi][k], v[k]);
        dsum += (double)df * (double)df;
        qW2[(size_t)(2 * g + (k & 1)) * F + 8 * c + (k >> 1)] = __fadd_rn(v[k], df);
    }
    block_partial(dsum, pbuf);
}

// ---------------- BN stats: numpy sequential fp32, double-buffered loads ----------------
__global__ __launch_bounds__(64) void k_bn(
    const float* __restrict__ qx, float* __restrict__ mu, float* __restrict__ rs)
{
    const int f = blockIdx.x * 64 + threadIdx.x;   // 8 blocks x 64 threads = 512 cols
    const float* col = qx + f;

    float bufA[16], bufB[16];
    // ---- pass 1: mean ----
    #pragma unroll
    for (int j = 0; j < 16; ++j) bufA[j] = col[(size_t)j * F];
    float acc = 0.f;
    for (int b = 0; b < 128; ++b) {            // 128 iters x 32 rows
        const int base = b * 32;
        #pragma unroll
        for (int j = 0; j < 16; ++j) bufB[j] = col[(size_t)(base + 16 + j) * F];
        #pragma unroll
        for (int j = 0; j < 16; ++j) acc = __fadd_rn(acc, bufA[j]);
        if (b < 127) {
            #pragma unroll
            for (int j = 0; j < 16; ++j) bufA[j] = col[(size_t)(base + 32 + j) * F];
        }
        #pragma unroll
        for (int j = 0; j < 16; ++j) acc = __fadd_rn(acc, bufB[j]);
    }
    const float m = __fmul_rn(acc, 1.f / 4096.f);   // exact (/2^12)

    // ---- pass 2: biased var, numpy order ----
    #pragma unroll
    for (int j = 0; j < 16; ++j) bufA[j] = col[(size_t)j * F];
    float acc2 = 0.f;
    for (int b = 0; b < 128; ++b) {
        const int base = b * 32;
        #pragma unroll
        for (int j = 0; j < 16; ++j) bufB[j] = col[(size_t)(base + 16 + j) * F];
        #pragma unroll
        for (int j = 0; j < 16; ++j) {
            float d = __fsub_rn(bufA[j], m);
            acc2 = __fadd_rn(acc2, __fmul_rn(d, d));
        }
        if (b < 127) {
            #pragma unroll
            for (int j = 0; j < 16; ++j) bufA[j] = col[(size_t)(base + 32 + j) * F];
        }
        #pragma unroll
        for (int j = 0; j < 16; ++j) {
            float d = __fsub_rn(bufB[j], m);
            acc2 = __fadd_rn(acc2, __fmul_rn(d, d));
        }
    }
    float var = __fmul_rn(acc2, 1.f / 4096.f);
    float w = __fadd_rn(var, 1e-5f);
    mu[f] = m;
    rs[f] = __fdiv_rn(1.0f, __fsqrt_rn(w));
}

// ---------------- fq22: dim-2 VQ via spatial-grid pruned search ----------------
__global__ __launch_bounds__(256) void k_fq22_np(
    const float* __restrict__ h2, const float* __restrict__ ecb3,
    const int* __restrict__ gcnt, const short* __restrict__ glist,
    float* __restrict__ qx2, double* __restrict__ pbuf)
{
    __shared__ float4 EsL[NEC];
    const int t = threadIdx.x;
    for (int n = t; n < NEC; n += 256)
        EsL[n] = reinterpret_cast<const float4*>(ecb3)[n];
    __syncthreads();
    const int b = blockIdx.x;
    const float v0 = h2[(size_t)b * F + t];         // >= 0 (relu)
    const float v1 = h2[(size_t)b * F + 256 + t];   // >= 0
    const float Aterm = __fadd_rn(__fmul_rn(v0, v0), __fmul_rn(v1, v1));
    float best = 3.4e38f; int bi = 0;
    const bool inbox = (v0 < 16.f) && (v1 < 16.f);
    int cx = (int)(v0 * 4.f), cy = (int)(v1 * 4.f);
    int cell = (cy << 6) + cx;
    int cnt = inbox ? gcnt[cell] : (NEC + 1);       // out-of-box -> full scan
    if (cnt <= GCAP) {
        const short* lst = glist + (size_t)cell * GCAP;
        int i = 0;
        const int cnt4 = cnt & ~3;
        for (; i < cnt4; i += 4) {                   // one 8B gather per 4 ids
            ushort4 ids = *reinterpret_cast<const ushort4*>(lst + i);
            float4 ea = EsL[ids.x];
            float4 eb = EsL[ids.y];
            float4 ec = EsL[ids.z];
            float4 ed = EsL[ids.w];
            float ba = fmaf(v1, ea.y, __fmul_rn(v0, ea.x));
            float da = __fadd_rn(__fsub_rn(Aterm, __fadd_rn(ba, ba)), ea.z);
            if (da < best) { best = da; bi = ids.x; }
            float bb = fmaf(v1, eb.y, __fmul_rn(v0, eb.x));
            float db = __fadd_rn(__fsub_rn(Aterm, __fadd_rn(bb, bb)), eb.z);
            if (db < best) { best = db; bi = ids.y; }
            float bc = fmaf(v1, ec.y, __fmul_rn(v0, ec.x));
            float dc = __fadd_rn(__fsub_rn(Aterm, __fadd_rn(bc, bc)), ec.z);
            if (dc < best) { best = dc; bi = ids.z; }
            float bd = fmaf(v1, ed.y, __fmul_rn(v0, ed.x));
            float dd = __fadd_rn(__fsub_rn(Aterm, __fadd_rn(bd, bd)), ed.z);
            if (dd < best) { best = dd; bi = ids.w; }
        }
        for (; i < cnt; ++i) {
            int id = lst[i];
            float4 e = EsL[id];
            float bsum = fmaf(v1, e.y, __fmul_rn(v0, e.x));
            float d = __fadd_rn(__fsub_rn(Aterm, __fadd_rn(bsum, bsum)), e.z);
            if (d < best) { best = d; bi = id; }
        }
    } else {
        for (int n = 0; n < NEC; ++n) {
            float4 e = EsL[n];
            float bsum = fmaf(v1, e.y, __fmul_rn(v0, e.x));
            float d = __fadd_rn(__fsub_rn(Aterm, __fadd_rn(bsum, bsum)), e.z);
            if (d < best) { best = d; bi = n; }
        }
    }
    float4 eb = EsL[bi];
    float d0 = __fsub_rn(eb.x, v0), d1 = __fsub_rn(eb.y, v1);
    qx2[(size_t)b * F + t]       = __fadd_rn(v0, d0);
    qx2[(size_t)b * F + 256 + t] = __fadd_rn(v1, d1);
    block_partial((double)d0 * d0 + (double)d1 * d1, pbuf);
}

// ---------------- final thin GEMM: out[b,o] = sum_i qx2[b,i] * W3[o,i] ----------------
__global__ __launch_bounds__(256) void k_gemm3(
    const float* __restrict__ qx2, const float* __restrict__ W3, float* __restrict__ out)
{
    __shared__ float Ws[10 * F];
    const int t = threadIdx.x;
    for (int i = t; i < 10 * F; i += 256) Ws[i] = W3[i];
    __syncthreads();
    const int w = t >> 6, l = t & 63;
    const int b = blockIdx.x * 4 + w;
    const float* xb = qx2 + (size_t)b * F;
    double acc[10] = {};
    for (int i = l; i < F; i += 64) {
        double xv = (double)xb[i];
        #pragma unroll
        for (int o = 0; o < 10; ++o) acc[o] = fma(xv, (double)Ws[o * F + i], acc[o]);
    }
    #pragma unroll
    for (int o = 0; o < 10; ++o) {
        double a = wave_reduce_add(acc[o]);
        if (l == 0) out[(size_t)b * 10 + o] = (float)a;
    }
}

// ---------------- deterministic diff reduction ----------------
__global__ __launch_bounds__(256) void k_reduce(
    const double* __restrict__ p21, const double* __restrict__ pwq,
    const double* __restrict__ p22, float* __restrict__ out)
{
    __shared__ double sd[256];
    __shared__ double res[3];
    const int t = threadIdx.x;
    // --- p21 (1024) ---
    double s = 0.0;
    for (int i = t; i < 1024; i += 256) s += p21[i];
    sd[t] = s; __syncthreads();
    for (int o = 128; o; o >>= 1) { if (t < o) sd[t] += sd[t + o]; __syncthreads(); }
    if (t == 0) res[0] = sd[0];
    __syncthreads();
    // --- pwq (64) ---
    s = (t < 64) ? pwq[t] : 0.0;
    sd[t] = s; __syncthreads();
    for (int o = 128; o; o >>= 1) { if (t < o) sd[t] += sd[t + o]; __syncthreads(); }
    if (t == 0) res[1] = sd[0];
    __syncthreads();
    // --- p22 (4096) ---
    s = 0.0;
    for (int i = t; i < 4096; i += 256) s += p22[i];
    sd[t] = s; __syncthreads();
    for (int o = 128; o; o >>= 1) { if (t < o) sd[t] += sd[t + o]; __syncthreads(); }
    if (t == 0) {
        double d21 = res[0] * (1.0 / 2097152.0);   // 4096*64*8
        double dq  = res[1] * (1.0 / 262144.0);    // 256*64*16
        double d22 = sd[0]  * (1.0 / 2097152.0);   // 4096*256*2
        out[BATCH * 10] = (float)((d21 + d22) + dq);
    }
}

extern "C" void kernel_launch(void* const* d_in, const int* in_sizes, int n_in,
                              void* d_out, int out_size, void* d_ws, size_t ws_size,
                              hipStream_t stream)
{
    const float* x     = (const float*)d_in[0];
    const float* W1    = (const float*)d_in[1];
    const float* W2    = (const float*)d_in[2];
    const float* W3    = (const float*)d_in[3];
    const float* gamma = (const float*)d_in[4];
    const float* beta  = (const float*)d_in[5];
    const float* E1    = (const float*)d_in[6];   // [8,512]
    const float* E2    = (const float*)d_in[7];   // [16,512]
    const float* E3    = (const float*)d_in[8];   // [2,512]
    float* out = (float*)d_out;

    const int KC = 512;   // confirmed round 4 (BLIS/zen single-panel for K=512)

    char* ws = (char*)d_ws;
    float*  hf    = (float*)ws;                                 // 8 MB (h, then h2)
    float*  qxf   = (float*)(ws + (size_t) 8 * 1024 * 1024);    // 8 MB (qx, then qx2)
    float*  qW2f  = (float*)(ws + (size_t)16 * 1024 * 1024);    // 1 MB
    float*  muf   = (float*)(ws + (size_t)17 * 1024 * 1024);    // 512 f32
    float*  rsf   = muf + F;                                    // 512 f32
    float*  ecb3  = (float*)(ws + (size_t)17 * 1024 * 1024 + 8192);    // 512*4 f32
    int*    gcnt  = (int*)(ws + (size_t)18 * 1024 * 1024);      // 4096 int
    short*  glist = (short*)(ws + (size_t)18 * 1024 * 1024 + 16384);   // 4096*96 i16
    double* p21   = (double*)(ws + (size_t)19 * 1024 * 1024);   // 1024 f64
    double* pwq   = p21 + 1024;                                 // 64 f64
    double* p22   = pwq + 64;                                   // 4096 f64

    k_prep<<<8, 64, 0, stream>>>(E3, ecb3);
    k_grid<<<16, 256, 0, stream>>>(E3, gcnt, glist);
    // h = relu(x @ W1^T)  — sgemm emulation, KC panels (784 = 512 + 272)
    k_gemm_np<true, false><<<dim3(F / 64, BATCH / 64), 256, 0, stream>>>(
        x, W1, hf, BATCH, F, D_IN, KC, nullptr, nullptr, nullptr, nullptr);
    // fq21 -> qx
    k_fq21_np<<<BATCH * 64 / 256, 256, 0, stream>>>(hf, E1, qxf, p21);
    // weight quantization -> qW2
    k_wq_np<<<64, 256, 0, stream>>>(W2, E2, qW2f, pwq);
    // BN stats (sequential fp32, numpy order; latency-hidden)
    k_bn<<<8, 64, 0, stream>>>(qxf, muf, rsf);
    // h2 = relu(bn(qx) @ qW2^T) — K=512 = single panel -> pure sequential fma
    k_gemm_np<true, true><<<dim3(F / 64, BATCH / 64), 256, 0, stream>>>(
        qxf, qW2f, hf, BATCH, F, F, KC, muf, rsf, gamma, beta);
    // fq22 -> qx2 (grid-pruned, vectorized id gather)
    k_fq22_np<<<BATCH, 256, 0, stream>>>(hf, ecb3, gcnt, glist, qxf, p22);
    // out = qx2 @ W3^T
    k_gemm3<<<BATCH / 4, 256, 0, stream>>>(qxf, W3, out);
    // deterministic diff
    k_reduce<<<1, 256, 0, stream>>>(p21, pwq, p22, out);
}

// Round 9
// 388.082 us; speedup vs baseline: 1.9319x; 1.0418x over previous
//
#include <hip/hip_runtime.h>
#include <math.h>

constexpr int BATCH = 4096;
constexpr int D_IN  = 784;
constexpr int F     = 512;
constexpr int NEC   = 512;   // codebook entries

constexpr int   GRID_N = 64;     // fq22 spatial grid
constexpr float GCELL  = 0.25f;  // covers [0,16) x [0,16)
constexpr int   GCAP   = 96;     // max candidates per cell

// ---------------- prep: pack fq22 codebook {e0,e1,|e|^2,0} ----------------
__global__ void k_prep(const float* __restrict__ E3, float* __restrict__ ecb3)
{
    int n = blockIdx.x * 64 + threadIdx.x;
    if (n >= NEC) return;
    float a0 = E3[n], a1 = E3[NEC + n];
    float cn = __fadd_rn(__fmul_rn(a0, a0), __fmul_rn(a1, a1));
    reinterpret_cast<float4*>(ecb3)[n] = make_float4(a0, a1, cn, 0.f);
}

// ---------------- fq22 grid build: one thread per cell ----------------
__global__ void k_grid(const float* __restrict__ E3,
                       int* __restrict__ gcnt, short* __restrict__ glist)
{
    int cell = blockIdx.x * 256 + threadIdx.x;
    if (cell >= GRID_N * GRID_N) return;
    int cx = cell & (GRID_N - 1), cy = cell >> 6;
    float x0 = cx * GCELL, x1 = x0 + GCELL;
    float y0 = cy * GCELL, y1 = y0 + GCELL;
    float minUpper = 3.4e38f;
    for (int n = 0; n < NEC; ++n) {
        float ex = E3[n], ey = E3[NEC + n];
        float dxmax = fmaxf(x1 - ex, ex - x0);
        float dymax = fmaxf(y1 - ey, ey - y0);
        minUpper = fminf(minUpper, dxmax * dxmax + dymax * dymax);
    }
    float thr = minUpper + 0.01f;
    int cnt = 0;
    for (int n = 0; n < NEC; ++n) {
        float ex = E3[n], ey = E3[NEC + n];
        float dxmin = fmaxf(fmaxf(x0 - ex, ex - x1), 0.f);
        float dymin = fmaxf(fmaxf(y0 - ey, ey - y1), 0.f);
        if (dxmin * dxmin + dymin * dymin <= thr) {
            if (cnt < GCAP) glist[(size_t)cell * GCAP + cnt] = (short)n;
            ++cnt;
        }
    }
    gcnt[cell] = cnt;
}

// ---- GEMM (NT) emulating BLAS sgemm: per-output sequential-k fma chain
// ---- within KC-panels, panel partials combined in order with fp32 adds.
// ---- Double-buffered LDS (1 barrier/chunk) + register prefetch of next chunk.
template<bool RELU, bool BN>
__global__ __launch_bounds__(256) void k_gemm_np(
    const float* __restrict__ A, const float* __restrict__ Bw, float* __restrict__ C,
    int M, int N, int K, int KC,
    const float* __restrict__ mu, const float* __restrict__ rs,
    const float* __restrict__ gamma, const float* __restrict__ beta)
{
    __shared__ float As[2][16][68];
    __shared__ float Bs[2][16][68];
    const int t  = threadIdx.x;
    const int bm = blockIdx.y * 64, bn = blockIdx.x * 64;
    const int tm = (t >> 4) * 4, tn = (t & 15) * 4;
    const int rA = t >> 2;
    const int c4 = (t & 3) * 4;
    const float* Arow = A + (size_t)(bm + rA) * K + c4;
    const float* Brow = Bw + (size_t)(bn + rA) * K + c4;

    float tot[4][4];
    float accp[4][4] = {};
    bool first = true;

    // stage chunk 0
    {
        float4 af = *reinterpret_cast<const float4*>(Arow);
        float4 bf = *reinterpret_cast<const float4*>(Brow);
        float av[4] = {af.x, af.y, af.z, af.w};
        if (BN) {
            #pragma unroll
            for (int u = 0; u < 4; ++u) {
                const int k = c4 + u;
                float d = __fsub_rn(av[u], mu[k]);
                d = __fmul_rn(d, rs[k]);
                d = __fmul_rn(d, gamma[k]);
                av[u] = __fadd_rn(d, beta[k]);
            }
        }
        As[0][c4 + 0][rA] = av[0]; As[0][c4 + 1][rA] = av[1];
        As[0][c4 + 2][rA] = av[2]; As[0][c4 + 3][rA] = av[3];
        Bs[0][c4 + 0][rA] = bf.x;  Bs[0][c4 + 1][rA] = bf.y;
        Bs[0][c4 + 2][rA] = bf.z;  Bs[0][c4 + 3][rA] = bf.w;
    }
    __syncthreads();

    int cur = 0;
    for (int k0 = 0; k0 < K; k0 += 16) {
        const bool has_next = (k0 + 16) < K;
        float4 a_p, b_p;
        if (has_next) {                     // issue next-chunk loads early
            a_p = *reinterpret_cast<const float4*>(Arow + k0 + 16);
            b_p = *reinterpret_cast<const float4*>(Brow + k0 + 16);
        }
        #pragma unroll
        for (int kk = 0; kk < 16; ++kk) {
            float4 a4 = *reinterpret_cast<const float4*>(&As[cur][kk][tm]);
            float4 b4 = *reinterpret_cast<const float4*>(&Bs[cur][kk][tn]);
            float aa[4] = {a4.x, a4.y, a4.z, a4.w};
            float bb[4] = {b4.x, b4.y, b4.z, b4.w};
            #pragma unroll
            for (int i = 0; i < 4; ++i)
                #pragma unroll
                for (int j = 0; j < 4; ++j)
                    accp[i][j] = fmaf(aa[i], bb[j], accp[i][j]);
        }
        if (has_next) {
            float av[4] = {a_p.x, a_p.y, a_p.z, a_p.w};
            if (BN) {
                #pragma unroll
                for (int u = 0; u < 4; ++u) {
                    const int k = k0 + 16 + c4 + u;
                    float d = __fsub_rn(av[u], mu[k]);
                    d = __fmul_rn(d, rs[k]);
                    d = __fmul_rn(d, gamma[k]);
                    av[u] = __fadd_rn(d, beta[k]);
                }
            }
            const int alt = cur ^ 1;
            As[alt][c4 + 0][rA] = av[0]; As[alt][c4 + 1][rA] = av[1];
            As[alt][c4 + 2][rA] = av[2]; As[alt][c4 + 3][rA] = av[3];
            Bs[alt][c4 + 0][rA] = b_p.x; Bs[alt][c4 + 1][rA] = b_p.y;
            Bs[alt][c4 + 2][rA] = b_p.z; Bs[alt][c4 + 3][rA] = b_p.w;
        }
        __syncthreads();                    // single barrier per chunk
        const int kend = k0 + 16;
        if ((kend % KC) == 0 || kend == K) {   // panel boundary: fold partial
            #pragma unroll
            for (int i = 0; i < 4; ++i)
                #pragma unroll
                for (int j = 0; j < 4; ++j) {
                    tot[i][j] = first ? accp[i][j] : __fadd_rn(tot[i][j], accp[i][j]);
                    accp[i][j] = 0.f;
                }
            first = false;
        }
        cur ^= 1;
    }
    #pragma unroll
    for (int i = 0; i < 4; ++i) {
        float r0 = RELU ? fmaxf(tot[i][0], 0.f) : tot[i][0];
        float r1 = RELU ? fmaxf(tot[i][1], 0.f) : tot[i][1];
        float r2 = RELU ? fmaxf(tot[i][2], 0.f) : tot[i][2];
        float r3 = RELU ? fmaxf(tot[i][3], 0.f) : tot[i][3];
        float4 r = make_float4(r0, r1, r2, r3);
        *reinterpret_cast<float4*>(&C[(size_t)(bm + tm + i) * N + bn + tn]) = r;
    }
}

// ---------------- wave reduce + block partial helpers (no atomics) ----------------
__device__ __forceinline__ double wave_reduce_add(double v) {
    #pragma unroll
    for (int off = 32; off; off >>= 1) v += __shfl_xor(v, off);
    return v;
}

// 4-wave block: fixed-order fp64 partial -> pbuf[blockIdx.x]
__device__ __forceinline__ void block_partial(double dsum, double* pbuf) {
    __shared__ double wsum[4];
    const int t = threadIdx.x;
    dsum = wave_reduce_add(dsum);
    if ((t & 63) == 0) wsum[t >> 6] = dsum;
    __syncthreads();
    if (t == 0)
        pbuf[blockIdx.x] = ((wsum[0] + wsum[1]) + wsum[2]) + wsum[3];
}

// ---------------- fq21: dim-8 VQ, LDS codebook, index-only tracking ----------------
__global__ __launch_bounds__(256) void k_fq21_np(
    const float* __restrict__ h, const float* __restrict__ E,
    float* __restrict__ qx, double* __restrict__ pbuf)
{
    __shared__ float Es[NEC][8];
    __shared__ float Cn[NEC];
    const int t = threadIdx.x;
    for (int i = t; i < 8 * NEC; i += 256) Es[i & (NEC - 1)][i >> 9] = E[i];
    __syncthreads();
    for (int n = t; n < NEC; n += 256) {
        float c = __fmul_rn(Es[n][0], Es[n][0]);
        #pragma unroll
        for (int j = 1; j < 8; ++j)
            c = __fadd_rn(c, __fmul_rn(Es[n][j], Es[n][j]));
        Cn[n] = c;
    }
    __syncthreads();
    const int idx = blockIdx.x * 256 + t;
    const int b = idx >> 6, c = idx & 63;
    const float* hb = h + (size_t)b * F + c;
    float v[8];
    #pragma unroll
    for (int j = 0; j < 8; ++j) v[j] = hb[j * 64];
    float s[8];
    #pragma unroll
    for (int j = 0; j < 8; ++j) s[j] = __fmul_rn(v[j], v[j]);
    // numpy pairwise n=8: ((s0+s1)+(s2+s3)) + ((s4+s5)+(s6+s7))
    const float Aterm = __fadd_rn(
        __fadd_rn(__fadd_rn(s[0], s[1]), __fadd_rn(s[2], s[3])),
        __fadd_rn(__fadd_rn(s[4], s[5]), __fadd_rn(s[6], s[7])));
    float best = 3.4e38f; int bi = 0;
    for (int n = 0; n < NEC; ++n) {
        float4 e0 = *reinterpret_cast<const float4*>(&Es[n][0]);
        float4 e1 = *reinterpret_cast<const float4*>(&Es[n][4]);
        float bsum = __fmul_rn(v[0], e0.x);
        bsum = fmaf(v[1], e0.y, bsum);
        bsum = fmaf(v[2], e0.z, bsum);
        bsum = fmaf(v[3], e0.w, bsum);
        bsum = fmaf(v[4], e1.x, bsum);
        bsum = fmaf(v[5], e1.y, bsum);
        bsum = fmaf(v[6], e1.z, bsum);
        bsum = fmaf(v[7], e1.w, bsum);
        float d = __fadd_rn(__fsub_rn(Aterm, __fadd_rn(bsum, bsum)), Cn[n]);
        if (d < best) { best = d; bi = n; }
    }
    float4 q0 = *reinterpret_cast<const float4*>(&Es[bi][0]);
    float4 q1 = *reinterpret_cast<const float4*>(&Es[bi][4]);
    float bq[8] = {q0.x, q0.y, q0.z, q0.w, q1.x, q1.y, q1.z, q1.w};
    double dsum = 0.0;
    float* qb = qx + (size_t)b * F + c;
    #pragma unroll
    for (int j = 0; j < 8; ++j) {
        float df = __fsub_rn(bq[j], v[j]);        // fl(q - x)
        dsum += (double)df * (double)df;
        qb[j * 64] = __fadd_rn(v[j], df);         // fl(x + fl(q - x))
    }
    block_partial(dsum, pbuf);
}

// ---------------- weight quantization: dim-16 VQ (round-4 exact) ----------------
__global__ __launch_bounds__(256) void k_wq_np(
    const float* __restrict__ W2, const float* __restrict__ E,
    float* __restrict__ qW2, double* __restrict__ pbuf)
{
    __shared__ float Es[NEC][16];
    __shared__ float Cn[NEC];
    const int t = threadIdx.x;
    for (int i = t; i < 16 * NEC; i += 256) Es[i & (NEC - 1)][i >> 9] = E[i];
    __syncthreads();
    for (int n = t; n < NEC; n += 256) {
        float c = __fmul_rn(Es[n][0], Es[n][0]);
        #pragma unroll
        for (int j = 1; j < 16; ++j)
            c = __fadd_rn(c, __fmul_rn(Es[n][j], Es[n][j]));
        Cn[n] = c;
    }
    __syncthreads();
    const int idx = blockIdx.x * 256 + t;   // 16384 vectors
    const int g = idx >> 6, c = idx & 63;
    float v[16];
    #pragma unroll
    for (int k = 0; k < 16; ++k)
        v[k] = W2[(size_t)(2 * g + (k & 1)) * F + 8 * c + (k >> 1)];
    float s[16];
    #pragma unroll
    for (int k = 0; k < 16; ++k) s[k] = __fmul_rn(v[k], v[k]);
    float r[8];
    #pragma unroll
    for (int j = 0; j < 8; ++j) r[j] = __fadd_rn(s[j], s[j + 8]);
    const float Aterm = __fadd_rn(
        __fadd_rn(__fadd_rn(r[0], r[1]), __fadd_rn(r[2], r[3])),
        __fadd_rn(__fadd_rn(r[4], r[5]), __fadd_rn(r[6], r[7])));
    float best = 3.4e38f; int bi = 0;
    for (int n = 0; n < NEC; ++n) {
        float bsum = __fmul_rn(v[0], Es[n][0]);
        #pragma unroll
        for (int k = 1; k < 16; ++k) bsum = fmaf(v[k], Es[n][k], bsum);
        float d = __fadd_rn(__fsub_rn(Aterm, __fadd_rn(bsum, bsum)), Cn[n]);
        if (d < best) { best = d; bi = n; }
    }
    double dsum = 0.0;
    #pragma unroll
    for (int k = 0; k < 16; ++k) {
        float df = __fsub_rn(Es[bi][k], v[k]);
        dsum += (double)df * (double)df;
        qW2[(size_t)(2 * g + (k & 1)) * F + 8 * c + (k >> 1)] = __fadd_rn(v[k], df);
    }
    block_partial(dsum, pbuf);
}

// ---------------- BN stats: numpy sequential fp32, vmcnt-paced LDS ring ----------------
// 8 blocks x 64 threads (1 wave, no barriers). global_load_lds DMA into a 4-slot
// ring of [64 rows][64 cols] chunks; counted s_waitcnt vmcnt keeps 3 chunks
// (48 insts) in flight. Per-column add chain stays exact numpy row order.
__global__ __launch_bounds__(64) void k_bn(
    const float* __restrict__ qx, float* __restrict__ mu, float* __restrict__ rs)
{
    __shared__ float ring[4][64][64];   // 64 KB
    const int t  = threadIdx.x;
    const int f0 = blockIdx.x * 64;
    const int rr = t >> 4;              // row within 4-row segment
    const int cc = (t & 15) * 4;        // col offset (16B per lane)

#define BN_ISSUE(cn)                                                                  \
    {                                                                                 \
        const float* base_ = qx + (size_t)((cn) * 64 + rr) * F + f0 + cc;             \
        _Pragma("unroll")                                                             \
        for (int seg = 0; seg < 16; ++seg)                                            \
            __builtin_amdgcn_global_load_lds(                                         \
                (const __attribute__((address_space(1))) void*)(base_ + (size_t)seg * 4 * F), \
                (__attribute__((address_space(3))) void*)&ring[(cn) & 3][seg * 4][0], \
                16, 0, 0);                                                            \
    }

    // ---------- pass 1: mean ----------
    BN_ISSUE(0) BN_ISSUE(1) BN_ISSUE(2)
    float acc = 0.f;
    for (int c = 0; c < 64; ++c) {
        if (c < 62)       asm volatile("s_waitcnt vmcnt(32)" ::: "memory");
        else if (c == 62) asm volatile("s_waitcnt vmcnt(16)" ::: "memory");
        else              asm volatile("s_waitcnt vmcnt(0)"  ::: "memory");
        if (c <= 60) {
            asm volatile("s_waitcnt lgkmcnt(0)" ::: "memory");  // slot's old reads done
            BN_ISSUE(c + 3)
        }
        const float (*buf)[64] = ring[c & 3];
        #pragma unroll 16
        for (int r = 0; r < 64; ++r)
            acc = __fadd_rn(acc, buf[r][t]);
    }
    const float m = __fmul_rn(acc, 1.f / 4096.f);   // exact (/2^12)

    // ---------- pass 2: biased var, numpy order ----------
    BN_ISSUE(0) BN_ISSUE(1) BN_ISSUE(2)
    float acc2 = 0.f;
    for (int c = 0; c < 64; ++c) {
        if (c < 62)       asm volatile("s_waitcnt vmcnt(32)" ::: "memory");
        else if (c == 62) asm volatile("s_waitcnt vmcnt(16)" ::: "memory");
        else              asm volatile("s_waitcnt vmcnt(0)"  ::: "memory");
        if (c <= 60) {
            asm volatile("s_waitcnt lgkmcnt(0)" ::: "memory");
            BN_ISSUE(c + 3)
        }
        const float (*buf)[64] = ring[c & 3];
        #pragma unroll 16
        for (int r = 0; r < 64; ++r) {
            float d = __fsub_rn(buf[r][t], m);
            acc2 = __fadd_rn(acc2, __fmul_rn(d, d));
        }
    }
#undef BN_ISSUE
    float var = __fmul_rn(acc2, 1.f / 4096.f);
    float w = __fadd_rn(var, 1e-5f);
    mu[f0 + t] = m;
    rs[f0 + t] = __fdiv_rn(1.0f, __fsqrt_rn(w));
}

// ---------------- fq22: dim-2 VQ via spatial-grid pruned search ----------------
__global__ __launch_bounds__(256) void k_fq22_np(
    const float* __restrict__ h2, const float* __restrict__ ecb3,
    const int* __restrict__ gcnt, const short* __restrict__ glist,
    float* __restrict__ qx2, double* __restrict__ pbuf)
{
    __shared__ float4 EsL[NEC];
    const int t = threadIdx.x;
    for (int n = t; n < NEC; n += 256)
        EsL[n] = reinterpret_cast<const float4*>(ecb3)[n];
    __syncthreads();
    const int b = blockIdx.x;
    const float v0 = h2[(size_t)b * F + t];         // >= 0 (relu)
    const float v1 = h2[(size_t)b * F + 256 + t];   // >= 0
    const float Aterm = __fadd_rn(__fmul_rn(v0, v0), __fmul_rn(v1, v1));
    float best = 3.4e38f; int bi = 0;
    const bool inbox = (v0 < 16.f) && (v1 < 16.f);
    int cx = (int)(v0 * 4.f), cy = (int)(v1 * 4.f);
    int cell = (cy << 6) + cx;
    int cnt = inbox ? gcnt[cell] : (NEC + 1);       // out-of-box -> full scan
    if (cnt <= GCAP) {
        const short* lst = glist + (size_t)cell * GCAP;
        int i = 0;
        const int cnt4 = cnt & ~3;
        for (; i < cnt4; i += 4) {                   // one 8B gather per 4 ids
            ushort4 ids = *reinterpret_cast<const ushort4*>(lst + i);
            float4 ea = EsL[ids.x];
            float4 eb = EsL[ids.y];
            float4 ec = EsL[ids.z];
            float4 ed = EsL[ids.w];
            float ba = fmaf(v1, ea.y, __fmul_rn(v0, ea.x));
            float da = __fadd_rn(__fsub_rn(Aterm, __fadd_rn(ba, ba)), ea.z);
            if (da < best) { best = da; bi = ids.x; }
            float bb = fmaf(v1, eb.y, __fmul_rn(v0, eb.x));
            float db = __fadd_rn(__fsub_rn(Aterm, __fadd_rn(bb, bb)), eb.z);
            if (db < best) { best = db; bi = ids.y; }
            float bc = fmaf(v1, ec.y, __fmul_rn(v0, ec.x));
            float dc = __fadd_rn(__fsub_rn(Aterm, __fadd_rn(bc, bc)), ec.z);
            if (dc < best) { best = dc; bi = ids.z; }
            float bd = fmaf(v1, ed.y, __fmul_rn(v0, ed.x));
            float dd = __fadd_rn(__fsub_rn(Aterm, __fadd_rn(bd, bd)), ed.z);
            if (dd < best) { best = dd; bi = ids.w; }
        }
        for (; i < cnt; ++i) {
            int id = lst[i];
            float4 e = EsL[id];
            float bsum = fmaf(v1, e.y, __fmul_rn(v0, e.x));
            float d = __fadd_rn(__fsub_rn(Aterm, __fadd_rn(bsum, bsum)), e.z);
            if (d < best) { best = d; bi = id; }
        }
    } else {
        for (int n = 0; n < NEC; ++n) {
            float4 e = EsL[n];
            float bsum = fmaf(v1, e.y, __fmul_rn(v0, e.x));
            float d = __fadd_rn(__fsub_rn(Aterm, __fadd_rn(bsum, bsum)), e.z);
            if (d < best) { best = d; bi = n; }
        }
    }
    float4 eb = EsL[bi];
    float d0 = __fsub_rn(eb.x, v0), d1 = __fsub_rn(eb.y, v1);
    qx2[(size_t)b * F + t]       = __fadd_rn(v0, d0);
    qx2[(size_t)b * F + 256 + t] = __fadd_rn(v1, d1);
    block_partial((double)d0 * d0 + (double)d1 * d1, pbuf);
}

// ---------------- final thin GEMM: out[b,o] = sum_i qx2[b,i] * W3[o,i] ----------------
__global__ __launch_bounds__(256) void k_gemm3(
    const float* __restrict__ qx2, const float* __restrict__ W3, float* __restrict__ out)
{
    __shared__ float Ws[10 * F];
    const int t = threadIdx.x;
    for (int i = t; i < 10 * F; i += 256) Ws[i] = W3[i];
    __syncthreads();
    const int w = t >> 6, l = t & 63;
    const int b = blockIdx.x * 4 + w;
    const float* xb = qx2 + (size_t)b * F;
    double acc[10] = {};
    for (int i = l; i < F; i += 64) {
        double xv = (double)xb[i];
        #pragma unroll
        for (int o = 0; o < 10; ++o) acc[o] = fma(xv, (double)Ws[o * F + i], acc[o]);
    }
    #pragma unroll
    for (int o = 0; o < 10; ++o) {
        double a = wave_reduce_add(acc[o]);
        if (l == 0) out[(size_t)b * 10 + o] = (float)a;
    }
}

// ---------------- deterministic diff reduction ----------------
__global__ __launch_bounds__(256) void k_reduce(
    const double* __restrict__ p21, const double* __restrict__ pwq,
    const double* __restrict__ p22, float* __restrict__ out)
{
    __shared__ double sd[256];
    __shared__ double res[3];
    const int t = threadIdx.x;
    // --- p21 (1024) ---
    double s = 0.0;
    for (int i = t; i < 1024; i += 256) s += p21[i];
    sd[t] = s; __syncthreads();
    for (int o = 128; o; o >>= 1) { if (t < o) sd[t] += sd[t + o]; __syncthreads(); }
    if (t == 0) res[0] = sd[0];
    __syncthreads();
    // --- pwq (64) ---
    s = (t < 64) ? pwq[t] : 0.0;
    sd[t] = s; __syncthreads();
    for (int o = 128; o; o >>= 1) { if (t < o) sd[t] += sd[t + o]; __syncthreads(); }
    if (t == 0) res[1] = sd[0];
    __syncthreads();
    // --- p22 (4096) ---
    s = 0.0;
    for (int i = t; i < 4096; i += 256) s += p22[i];
    sd[t] = s; __syncthreads();
    for (int o = 128; o; o >>= 1) { if (t < o) sd[t] += sd[t + o]; __syncthreads(); }
    if (t == 0) {
        double d21 = res[0] * (1.0 / 2097152.0);   // 4096*64*8
        double dq  = res[1] * (1.0 / 262144.0);    // 256*64*16
        double d22 = sd[0]  * (1.0 / 2097152.0);   // 4096*256*2
        out[BATCH * 10] = (float)((d21 + d22) + dq);
    }
}

extern "C" void kernel_launch(void* const* d_in, const int* in_sizes, int n_in,
                              void* d_out, int out_size, void* d_ws, size_t ws_size,
                              hipStream_t stream)
{
    const float* x     = (const float*)d_in[0];
    const float* W1    = (const float*)d_in[1];
    const float* W2    = (const float*)d_in[2];
    const float* W3    = (const float*)d_in[3];
    const float* gamma = (const float*)d_in[4];
    const float* beta  = (const float*)d_in[5];
    const float* E1    = (const float*)d_in[6];   // [8,512]
    const float* E2    = (const float*)d_in[7];   // [16,512]
    const float* E3    = (const float*)d_in[8];   // [2,512]
    float* out = (float*)d_out;

    const int KC = 512;   // confirmed round 4 (BLIS/zen single-panel for K=512)

    char* ws = (char*)d_ws;
    float*  hf    = (float*)ws;                                 // 8 MB (h, then h2)
    float*  qxf   = (float*)(ws + (size_t) 8 * 1024 * 1024);    // 8 MB (qx, then qx2)
    float*  qW2f  = (float*)(ws + (size_t)16 * 1024 * 1024);    // 1 MB
    float*  muf   = (float*)(ws + (size_t)17 * 1024 * 1024);    // 512 f32
    float*  rsf   = muf + F;                                    // 512 f32
    float*  ecb3  = (float*)(ws + (size_t)17 * 1024 * 1024 + 8192);    // 512*4 f32
    int*    gcnt  = (int*)(ws + (size_t)18 * 1024 * 1024);      // 4096 int
    short*  glist = (short*)(ws + (size_t)18 * 1024 * 1024 + 16384);   // 4096*96 i16
    double* p21   = (double*)(ws + (size_t)19 * 1024 * 1024);   // 1024 f64
    double* pwq   = p21 + 1024;                                 // 64 f64
    double* p22   = pwq + 64;                                   // 4096 f64

    k_prep<<<8, 64, 0, stream>>>(E3, ecb3);
    k_grid<<<16, 256, 0, stream>>>(E3, gcnt, glist);
    // h = relu(x @ W1^T)  — sgemm emulation, KC panels (784 = 512 + 272)
    k_gemm_np<true, false><<<dim3(F / 64, BATCH / 64), 256, 0, stream>>>(
        x, W1, hf, BATCH, F, D_IN, KC, nullptr, nullptr, nullptr, nullptr);
    // fq21 -> qx
    k_fq21_np<<<BATCH * 64 / 256, 256, 0, stream>>>(hf, E1, qxf, p21);
    // weight quantization -> qW2
    k_wq_np<<<64, 256, 0, stream>>>(W2, E2, qW2f, pwq);
    // BN stats (sequential fp32, numpy order; vmcnt-paced ring)
    k_bn<<<8, 64, 0, stream>>>(qxf, muf, rsf);
    // h2 = relu(bn(qx) @ qW2^T) — K=512 = single panel -> pure sequential fma
    k_gemm_np<true, true><<<dim3(F / 64, BATCH / 64), 256, 0, stream>>>(
        qxf, qW2f, hf, BATCH, F, F, KC, muf, rsf, gamma, beta);
    // fq22 -> qx2 (grid-pruned, vectorized id gather)
    k_fq22_np<<<BATCH, 256, 0, stream>>>(hf, ecb3, gcnt, glist, qxf, p22);
    // out = qx2 @ W3^T
    k_gemm3<<<BATCH / 4, 256, 0, stream>>>(qxf, W3, out);
    // deterministic diff
    k_reduce<<<1, 256, 0, stream>>>(p21, pwq, p22, out);
}